// Round 13
// baseline (669.952 us; speedup 1.0000x reference)
//
#include <hip/hip_runtime.h>
#include <hip/hip_bf16.h>

// Problem constants
#define B_   4
#define T_   32
#define N_   370
#define E_   11840
#define E2_  12210          // E_ + N_ self loops
#define H_   64
#define G_   128            // B_*T_
#define GN_  47360          // G_*N_
#define BN_  1480           // B_*N_
#define NH_  23680          // N_*H_
#define ECAP 320            // LDS edge-stage capacity per node (max deg ~70)
#define KC_  148            // mlp1 k-chunk (23680 = 148*160)
#define NKC_ 160            // number of k-chunks

__device__ __forceinline__ float gelu_f(float x){
  return 0.5f * x * (1.0f + erff(x * 0.7071067811865475f));
}
__device__ __forceinline__ float wsum64(float v){
  #pragma unroll
  for (int m = 32; m > 0; m >>= 1) v += __shfl_xor(v, m, 64);
  return v;
}
__device__ __forceinline__ float lrelu(float v){ return v > 0.f ? v : 0.2f * v; }

// ---------- edge preprocessing ----------
__global__ void k_deg_count(const int* __restrict__ ei, const float* __restrict__ ew,
                            float* __restrict__ deg, int* __restrict__ counts){
  int e = blockIdx.x * 256 + threadIdx.x;
  if (e >= E2_) return;
  int dst = (e < E_) ? ei[E_ + e] : (e - E_);
  float w = (e < E_) ? ew[e] : 1.0f;
  atomicAdd(&deg[dst], w);
  atomicAdd(&counts[dst], 1);
}

__global__ void k_gnorm(const int* __restrict__ ei, const float* __restrict__ ew,
                        const float* __restrict__ deg, float* __restrict__ gnorm){
  int e = blockIdx.x * 256 + threadIdx.x;
  if (e >= E2_) return;
  int s = (e < E_) ? ei[e] : (e - E_);
  int d = (e < E_) ? ei[E_ + e] : (e - E_);
  float w = (e < E_) ? ew[e] : 1.0f;
  float ds = deg[s] > 0.f ? rsqrtf(deg[s]) : 0.f;
  float dd = deg[d] > 0.f ? rsqrtf(deg[d]) : 0.f;
  gnorm[e] = ds * w * dd;
}

// wave-parallel exclusive scan over counts (one wave)
__global__ void k_scan(const int* __restrict__ counts, int* __restrict__ offs,
                       int* __restrict__ cursor){
  int lane = threadIdx.x;
  int run = 0;
  for (int c0 = 0; c0 < N_; c0 += 64){
    int n = c0 + lane;
    int v = (n < N_) ? counts[n] : 0;
    int s = v;
    #pragma unroll
    for (int m = 1; m < 64; m <<= 1){
      int t = __shfl_up(s, m, 64);
      if (lane >= m) s += t;
    }
    int excl = run + s - v;
    if (n < N_){ offs[n] = excl; cursor[n] = excl; }
    run += __shfl(s, 63, 64);
  }
  if (lane == 0) offs[N_] = run;
}

// stores PRE-SCALED source offset s*64 + packed (soff, gnorm) pairs
__global__ void k_fill(const int* __restrict__ ei, const float* __restrict__ gnorm,
                       int* __restrict__ cursor, int* __restrict__ csr_soff,
                       float* __restrict__ csr_g, int2* __restrict__ epack){
  int e = blockIdx.x * 256 + threadIdx.x;
  if (e >= E2_) return;
  int s = (e < E_) ? ei[e] : (e - E_);
  int d = (e < E_) ? ei[E_ + e] : (e - E_);
  int pos = atomicAdd(&cursor[d], 1);
  csr_soff[pos] = s * 64;
  float gw = gnorm[e];
  csr_g[pos] = gw;
  epack[pos] = make_int2(s * 64, __float_as_int(gw));
}

// transpose temporal-conv weights: WT[l][(ci*5+k)*64 + ho] = W_t[l][ho*320+ci*5+k]
__global__ void k_wtr(const float* __restrict__ Wt, float* __restrict__ WT){
  int i = blockIdx.x * 256 + threadIdx.x;     // 3*20480 exact
  int l = i / 20480, rem = i - l * 20480;
  int ho = rem / 320, j = rem - ho * 320;
  WT[l * 20480 + j * 64 + ho] = Wt[i];
}

// rows x 64 @ 64 x 64 -> rows x 64 ; 64 rows/block, 4x4 register tile
__global__ __launch_bounds__(256) void k_rowgemm(const float* __restrict__ in,
                                                 const float* __restrict__ W,
                                                 float* __restrict__ outp){
  __shared__ float Ws[64 * 64];     // [k][col]
  __shared__ float rsT[64 * 68];    // [k][row], padded
  int tid = threadIdx.x;
  size_t r0 = (size_t)blockIdx.x * 64;
  #pragma unroll
  for (int i = tid; i < 1024; i += 256)
    *(float4*)&Ws[i * 4] = *(const float4*)&W[i * 4];
  #pragma unroll
  for (int i = tid; i < 1024; i += 256){
    int r = i >> 4, k4 = (i & 15) * 4;
    float4 v = *(const float4*)&in[(r0 + r) * 64 + k4];
    rsT[(k4 + 0) * 68 + r] = v.x;
    rsT[(k4 + 1) * 68 + r] = v.y;
    rsT[(k4 + 2) * 68 + r] = v.z;
    rsT[(k4 + 3) * 68 + r] = v.w;
  }
  __syncthreads();
  int c0 = (tid & 15) * 4;
  int rr0 = (tid >> 4) * 4;
  float4 a0 = {0,0,0,0}, a1 = {0,0,0,0}, a2 = {0,0,0,0}, a3 = {0,0,0,0};
  #pragma unroll 4
  for (int k = 0; k < 64; ++k){
    float4 rv = *(const float4*)&rsT[k * 68 + rr0];
    float4 wv = *(const float4*)&Ws[k * 64 + c0];
    a0.x += rv.x*wv.x; a0.y += rv.x*wv.y; a0.z += rv.x*wv.z; a0.w += rv.x*wv.w;
    a1.x += rv.y*wv.x; a1.y += rv.y*wv.y; a1.z += rv.y*wv.z; a1.w += rv.y*wv.w;
    a2.x += rv.z*wv.x; a2.y += rv.z*wv.y; a2.z += rv.z*wv.z; a2.w += rv.z*wv.w;
    a3.x += rv.w*wv.x; a3.y += rv.w*wv.y; a3.z += rv.w*wv.z; a3.w += rv.w*wv.w;
  }
  *(float4*)&outp[(r0 + rr0 + 0) * 64 + c0] = a0;
  *(float4*)&outp[(r0 + rr0 + 1) * 64 + c0] = a1;
  *(float4*)&outp[(r0 + rr0 + 2) * 64 + c0] = a2;
  *(float4*)&outp[(r0 + rr0 + 3) * 64 + c0] = a3;
}

// GCN aggregate v4: block = (node n, group of 16 graphs); 4 graphs per wave.
__global__ __launch_bounds__(256) void k_gcn_agg(const float* __restrict__ hw,
    const int2* __restrict__ epack, const int* __restrict__ offs,
    const float* __restrict__ b_gcn, float* __restrict__ gout){
  __shared__ int2 eS[ECAP];
  int nb = blockIdx.x;              // 0..2959
  int n = nb % N_;
  int gg = nb / N_;                 // 0..7
  int tid = threadIdx.x;
  int o0 = offs[n], o1 = offs[n + 1];
  int deg = o1 - o0;
  int cap = deg < ECAP ? deg : ECAP;
  for (int i = tid; i < cap; i += 256) eS[i] = epack[o0 + i];
  __syncthreads();
  int wv = tid >> 6, c = tid & 63;
  int g0 = gg * 16 + wv * 4;
  const float* h0 = hw + (size_t)(g0 + 0) * NH_;
  const float* h1 = hw + (size_t)(g0 + 1) * NH_;
  const float* h2 = hw + (size_t)(g0 + 2) * NH_;
  const float* h3 = hw + (size_t)(g0 + 3) * NH_;
  float a0 = 0.f, a1 = 0.f, a2 = 0.f, a3 = 0.f;
  int p = 0;
  for (; p + 4 <= cap; p += 4){
    int2 ea = eS[p+0], eb = eS[p+1], ec = eS[p+2], ed = eS[p+3];
    float wa = __int_as_float(ea.y), wb = __int_as_float(eb.y);
    float wc = __int_as_float(ec.y), wd = __int_as_float(ed.y);
    float va0 = h0[ea.x+c], va1 = h1[ea.x+c], va2 = h2[ea.x+c], va3 = h3[ea.x+c];
    float vb0 = h0[eb.x+c], vb1 = h1[eb.x+c], vb2 = h2[eb.x+c], vb3 = h3[eb.x+c];
    float vc0 = h0[ec.x+c], vc1 = h1[ec.x+c], vc2 = h2[ec.x+c], vc3 = h3[ec.x+c];
    float vd0 = h0[ed.x+c], vd1 = h1[ed.x+c], vd2 = h2[ed.x+c], vd3 = h3[ed.x+c];
    a0 += wa*va0 + wb*vb0 + wc*vc0 + wd*vd0;
    a1 += wa*va1 + wb*vb1 + wc*vc1 + wd*vd1;
    a2 += wa*va2 + wb*vb2 + wc*vc2 + wd*vd2;
    a3 += wa*va3 + wb*vb3 + wc*vc3 + wd*vd3;
  }
  for (; p < cap; ++p){
    int2 e = eS[p];
    float w = __int_as_float(e.y);
    a0 += w * h0[e.x+c]; a1 += w * h1[e.x+c];
    a2 += w * h2[e.x+c]; a3 += w * h3[e.x+c];
  }
  for (int q = cap; q < deg; ++q){      // overflow fallback (not expected)
    int2 e = epack[o0 + q];
    float w = __int_as_float(e.y);
    a0 += w * h0[e.x+c]; a1 += w * h1[e.x+c];
    a2 += w * h2[e.x+c]; a3 += w * h3[e.x+c];
  }
  float bv = b_gcn[c];
  gout[((size_t)(g0+0) * N_ + n) * 64 + c] = gelu_f(a0 + bv);
  gout[((size_t)(g0+1) * N_ + n) * 64 + c] = gelu_f(a1 + bv);
  gout[((size_t)(g0+2) * N_ + n) * 64 + c] = gelu_f(a2 + bv);
  gout[((size_t)(g0+3) * N_ + n) * 64 + c] = gelu_f(a3 + bv);
}

// attention scores per (g,n,head)
__global__ void k_attn(const float* __restrict__ gh, const float* __restrict__ att_s,
                       const float* __restrict__ att_d, float* __restrict__ asrc,
                       float* __restrict__ adst){
  int idx = blockIdx.x * 256 + threadIdx.x;   // GN_*4 exact
  int head = idx & 3;
  int gn = idx >> 2;
  const float* row = gh + (size_t)gn * 64 + head * 16;
  float as = 0.f, ad = 0.f;
  #pragma unroll
  for (int d = 0; d < 16; ++d){
    float v = row[d];
    as += v * att_s[head * 16 + d];
    ad += v * att_d[head * 16 + d];
  }
  asrc[idx] = as;
  adst[idx] = ad;
}

// per (g,n,head): softmax max+denominator over incoming edges;
// writes UNNORMALIZED exp weights alpha[g][p][head] and invden[g][n][head]
__global__ void k_alpha(const float* __restrict__ asrc, const float* __restrict__ adst,
                        const int* __restrict__ csr_soff, const int* __restrict__ offs,
                        float* __restrict__ alpha, float* __restrict__ invden){
  int idx = blockIdx.x * 256 + threadIdx.x;   // (g*N+n)*4+head, GN_*4 exact
  int head = idx & 3;
  int gn = idx >> 2;
  int g = gn / N_, n = gn - g * N_;
  int o0 = offs[n], o1 = offs[n + 1];
  const float* as_g = asrc + (size_t)g * (N_ * 4);
  float adv = adst[idx];
  float m = -1e30f;
  int p = o0;
  for (; p + 4 <= o1; p += 4){
    int sa = csr_soff[p+0] >> 4, sb = csr_soff[p+1] >> 4;
    int sc = csr_soff[p+2] >> 4, sd = csr_soff[p+3] >> 4;
    float va = lrelu(as_g[sa + head] + adv);
    float vb = lrelu(as_g[sb + head] + adv);
    float vc = lrelu(as_g[sc + head] + adv);
    float vd = lrelu(as_g[sd + head] + adv);
    m = fmaxf(m, fmaxf(fmaxf(va, vb), fmaxf(vc, vd)));
  }
  for (; p < o1; ++p)
    m = fmaxf(m, lrelu(as_g[(csr_soff[p] >> 4) + head] + adv));
  float* al_g = alpha + (size_t)g * (E2_ * 4);
  float den = 0.f;
  p = o0;
  for (; p + 4 <= o1; p += 4){
    int sa = csr_soff[p+0] >> 4, sb = csr_soff[p+1] >> 4;
    int sc = csr_soff[p+2] >> 4, sd = csr_soff[p+3] >> 4;
    float ea = __expf(lrelu(as_g[sa + head] + adv) - m);
    float eb = __expf(lrelu(as_g[sb + head] + adv) - m);
    float ec = __expf(lrelu(as_g[sc + head] + adv) - m);
    float ed = __expf(lrelu(as_g[sd + head] + adv) - m);
    den += ea + eb + ec + ed;
    al_g[(p+0)*4 + head] = ea;
    al_g[(p+1)*4 + head] = eb;
    al_g[(p+2)*4 + head] = ec;
    al_g[(p+3)*4 + head] = ed;
  }
  for (; p < o1; ++p){
    float ex = __expf(lrelu(as_g[(csr_soff[p] >> 4) + head] + adv) - m);
    den += ex;
    al_g[p*4 + head] = ex;
  }
  invden[idx] = 1.f / den;
}

// GAT aggregate v4: block = (node n, group of 16 graphs); 4 graphs per wave.
__global__ __launch_bounds__(256) void k_gat_agg(const float* __restrict__ gh,
    const float* __restrict__ alpha, const float* __restrict__ invden,
    const int* __restrict__ csr_soff, const int* __restrict__ offs,
    const float* __restrict__ b_gat, const float* __restrict__ ln_g,
    const float* __restrict__ ln_b, float* __restrict__ h){
  __shared__ int sS[ECAP];
  int nb = blockIdx.x;
  int n = nb % N_;
  int gg = nb / N_;
  int tid = threadIdx.x;
  int o0 = offs[n], o1 = offs[n + 1];
  int deg = o1 - o0;
  int cap = deg < ECAP ? deg : ECAP;
  for (int i = tid; i < cap; i += 256) sS[i] = csr_soff[o0 + i];
  __syncthreads();
  int wv = tid >> 6, c = tid & 63;
  int g0 = gg * 16 + wv * 4;
  int head = c >> 4;
  const float* gp0 = gh + (size_t)(g0 + 0) * NH_;
  const float* gp1 = gh + (size_t)(g0 + 1) * NH_;
  const float* gp2 = gh + (size_t)(g0 + 2) * NH_;
  const float* gp3 = gh + (size_t)(g0 + 3) * NH_;
  const float* al0 = alpha + (size_t)(g0 + 0) * (E2_ * 4) + (size_t)o0 * 4 + head;
  const float* al1 = alpha + (size_t)(g0 + 1) * (E2_ * 4) + (size_t)o0 * 4 + head;
  const float* al2 = alpha + (size_t)(g0 + 2) * (E2_ * 4) + (size_t)o0 * 4 + head;
  const float* al3 = alpha + (size_t)(g0 + 3) * (E2_ * 4) + (size_t)o0 * 4 + head;
  float a0 = 0.f, a1 = 0.f, a2 = 0.f, a3 = 0.f;
  int p = 0;
  for (; p + 2 <= cap; p += 2){
    int s0 = sS[p], s1 = sS[p+1];
    float x00 = al0[(p+0)*4], x01 = al0[(p+1)*4];
    float x10 = al1[(p+0)*4], x11 = al1[(p+1)*4];
    float x20 = al2[(p+0)*4], x21 = al2[(p+1)*4];
    float x30 = al3[(p+0)*4], x31 = al3[(p+1)*4];
    float v00 = gp0[s0+c], v01 = gp0[s1+c];
    float v10 = gp1[s0+c], v11 = gp1[s1+c];
    float v20 = gp2[s0+c], v21 = gp2[s1+c];
    float v30 = gp3[s0+c], v31 = gp3[s1+c];
    a0 += x00*v00 + x01*v01;
    a1 += x10*v10 + x11*v11;
    a2 += x20*v20 + x21*v21;
    a3 += x30*v30 + x31*v31;
  }
  for (; p < cap; ++p){
    int s = sS[p];
    a0 += al0[p*4] * gp0[s+c];
    a1 += al1[p*4] * gp1[s+c];
    a2 += al2[p*4] * gp2[s+c];
    a3 += al3[p*4] * gp3[s+c];
  }
  for (int q = cap; q < deg; ++q){
    int s = csr_soff[o0 + q];
    a0 += al0[q*4] * gp0[s+c];
    a1 += al1[q*4] * gp1[s+c];
    a2 += al2[q*4] * gp2[s+c];
    a3 += al3[q*4] * gp3[s+c];
  }
  float bgv = b_gat[c], lgv = ln_g[c], lbv = ln_b[c];
  float accs[4] = {a0, a1, a2, a3};
  #pragma unroll
  for (int q = 0; q < 4; ++q){
    int gn = (g0 + q) * N_ + n;
    float outv = accs[q] * invden[(size_t)gn * 4 + head] + bgv;
    size_t hidx = (size_t)gn * 64 + c;
    float r = outv + h[hidx];
    float mu = wsum64(r) * (1.f / 64.f);
    float d = r - mu;
    float var = wsum64(d * d) * (1.f / 64.f);
    h[hidx] = d * rsqrtf(var + 1e-5f) * lgv + lbv;
  }
}

// Fused temporal v5: ONE WAVE per (b,n), no barriers. lane = output channel ho,
// acc[32] covers all t. Per ci: 9 broadcast ds_read_b128 (conflict-free) +
// 5 coalesced W loads -> 160 FMA. In-place tile update is race-free by
// wave lockstep (all reads precede all writes in program order).
__global__ __launch_bounds__(64) void k_tfuse(const float* __restrict__ h,
    const float* __restrict__ WT, const float* __restrict__ bt,
    float* __restrict__ z){
  __shared__ float tile[64 * 36];        // padded x tile (rows 16B-aligned)
  int bn = blockIdx.x;
  int b = bn / N_, n = bn - b * N_;
  int lane = threadIdx.x;                // 0..63
  for (int i = lane; i < 2304; i += 64) tile[i] = 0.f;
  for (int i = lane; i < 2048; i += 64){
    int t = i >> 6, ch = i & 63;
    tile[ch * 36 + 2 + t] = h[((size_t)(b * T_ + t) * N_ + n) * 64 + ch];
  }
  int ho = lane;
  for (int l = 0; l < 3; ++l){
    const float* wl = WT + l * 20480 + ho;
    float bv = bt[l * 64 + ho];
    float acc[32];
    #pragma unroll
    for (int r = 0; r < 32; ++r) acc[r] = bv;
    for (int ci = 0; ci < 64; ++ci){
      const float* xr = &tile[ci * 36];      // xw[j] = x[ci][j-2]
      float4 xv[9];
      #pragma unroll
      for (int q = 0; q < 9; ++q) xv[q] = *(const float4*)&xr[q * 4];
      float xw[36];
      #pragma unroll
      for (int q = 0; q < 9; ++q){
        xw[q*4+0] = xv[q].x; xw[q*4+1] = xv[q].y;
        xw[q*4+2] = xv[q].z; xw[q*4+3] = xv[q].w;
      }
      const float* wp = wl + ci * 320;       // (ci*5+k)*64 + ho
      #pragma unroll
      for (int k = 0; k < 5; ++k){
        float w = wp[k * 64];
        #pragma unroll
        for (int r = 0; r < 32; ++r) acc[r] += xw[r + k] * w;
      }
    }
    // all tile reads for this layer are complete (wave lockstep); update own row
    #pragma unroll
    for (int r = 0; r < 32; ++r){
      float* tp = &tile[ho * 36 + 2 + r];
      *tp = gelu_f(acc[r]) + *tp;
    }
  }
  for (int i = lane; i < 2048; i += 64){
    int t = i >> 6, ch = i & 63;
    z[(size_t)(b * T_ + t) * NH_ + n * 64 + ch] = tile[ch * 36 + 2 + t];
  }
}

// MLP layer 1 (split-K, NO atomics): grid (4 b-groups, 160 kchunks of 148);
// each thread 8 rows x 4 cols; partials to private pbuf[kc] tile.
__global__ __launch_bounds__(256) void k_mlp1(const float* __restrict__ z,
    const float* __restrict__ W1, float* __restrict__ pbuf){
  __shared__ float zs[KC_ * 36];    // [j][r], r=0..31, stride 36
  int b = blockIdx.x;               // 0..3
  int kc = blockIdx.y;              // 0..159
  int base = kc * KC_;
  int tid = threadIdx.x;
  for (int i = tid; i < KC_ * 32; i += 256){
    int r = i / KC_, j = i - r * KC_;
    zs[j * 36 + r] = z[(size_t)(b * T_ + r) * NH_ + base + j];
  }
  __syncthreads();
  int r0 = (tid >> 6) * 8;
  int c0 = (tid & 63) * 4;
  float4 acc[8];
  #pragma unroll
  for (int r = 0; r < 8; ++r) acc[r] = (float4){0,0,0,0};
  const float* wbase = W1 + (size_t)base * 256 + c0;
  #pragma unroll 2
  for (int j = 0; j < KC_; ++j){
    float4 wv = *(const float4*)&wbase[(size_t)j * 256];
    float4 za = *(const float4*)&zs[j * 36 + r0];
    float4 zb = *(const float4*)&zs[j * 36 + r0 + 4];
    float zv[8] = {za.x, za.y, za.z, za.w, zb.x, zb.y, zb.z, zb.w};
    #pragma unroll
    for (int q = 0; q < 8; ++q){
      acc[q].x += zv[q]*wv.x; acc[q].y += zv[q]*wv.y;
      acc[q].z += zv[q]*wv.z; acc[q].w += zv[q]*wv.w;
    }
  }
  float* pb = pbuf + (size_t)kc * 32768;
  #pragma unroll
  for (int rr = 0; rr < 8; ++rr){
    int row = b * T_ + r0 + rr;
    *(float4*)&pb[(size_t)row * 256 + c0] = acc[rr];
  }
}

// reduce partials: y1[i] = sum_kc pbuf[kc*32768 + i]
__global__ __launch_bounds__(256) void k_red(const float* __restrict__ pbuf,
                                             float* __restrict__ y1){
  int i = blockIdx.x * 256 + threadIdx.x;   // 32768 exact
  float s0 = 0.f, s1 = 0.f, s2 = 0.f, s3 = 0.f;
  const float* p = pbuf + i;
  #pragma unroll 2
  for (int k = 0; k < NKC_; k += 4){
    s0 += p[(size_t)(k+0) * 32768];
    s1 += p[(size_t)(k+1) * 32768];
    s2 += p[(size_t)(k+2) * 32768];
    s3 += p[(size_t)(k+3) * 32768];
  }
  y1[i] = (s0 + s1) + (s2 + s3);
}

// MLP layer 2: out[128,64] = gelu(y1+b1) @ W2 + b2
__global__ __launch_bounds__(64) void k_mlp2(const float* __restrict__ y1,
    const float* __restrict__ b1, const float* __restrict__ W2,
    const float* __restrict__ b2, float* __restrict__ outp){
  __shared__ float a[256];
  int row = blockIdx.x, tid = threadIdx.x;
  for (int i = tid; i < 256; i += 64) a[i] = gelu_f(y1[(size_t)row * 256 + i] + b1[i]);
  __syncthreads();
  float acc = b2[tid];
  for (int i = 0; i < 256; ++i) acc += a[i] * W2[i * 64 + tid];
  outp[row * 64 + tid] = acc;
}

extern "C" void kernel_launch(void* const* d_in, const int* in_sizes, int n_in,
                              void* d_out, int out_size, void* d_ws, size_t ws_size,
                              hipStream_t stream){
  const float* x     = (const float*)d_in[0];
  const int*   ei    = (const int*)  d_in[1];
  const float* ew    = (const float*)d_in[2];
  const float* W_gcn = (const float*)d_in[3];
  const float* b_gcn = (const float*)d_in[4];
  const float* W_gat = (const float*)d_in[5];
  const float* att_s = (const float*)d_in[6];
  const float* att_d = (const float*)d_in[7];
  const float* b_gat = (const float*)d_in[8];
  const float* W_t   = (const float*)d_in[9];
  const float* b_t   = (const float*)d_in[10];
  const float* ln_g  = (const float*)d_in[11];
  const float* ln_b  = (const float*)d_in[12];
  const float* W1    = (const float*)d_in[13];
  const float* b1    = (const float*)d_in[14];
  const float* W2    = (const float*)d_in[15];
  const float* b2    = (const float*)d_in[16];
  float* outp = (float*)d_out;

  float* F = (float*)d_ws;
  size_t off = 0;
  float* deg    = F + off; off += 512;
  float* gnorm  = F + off; off += 12288;
  float* csr_g  = F + off; off += 12288;
  float* asrc   = F + off; off += 189440;
  float* adst   = F + off; off += 189440;
  float* invden = F + off; off += 189440;
  float* y1     = F + off; off += 32768;
  float* WT     = F + off; off += 61440;     // transposed temporal weights
  float* h      = F + off; off += 3031040;
  float* bufB   = F + off; off += 3031040;   // hw
  float* bufC   = F + off; off += 3031040;   // g
  float* bufD   = F + off; off += 3031040;   // gh / z
  float* alpha  = F + off; off += (size_t)G_ * E2_ * 4;   // 6,251,520 (reused as pbuf)
  float* pbuf   = alpha;                     // mlp1 partials: 160*32768 = 5,242,880 <= alpha
  int* I        = (int*)(F + off);
  int* counts   = I;
  int* offs     = I + 512;
  int* cursor   = I + 1024;
  int* csr_soff = I + 1536;                  // E2_ entries (12288 slot)
  int2* epack   = (int2*)(I + 13824);        // E2_ int2 entries

  hipMemsetAsync(deg, 0, 512 * sizeof(float), stream);
  hipMemsetAsync(counts, 0, 512 * sizeof(int), stream);

  k_deg_count<<<48, 256, 0, stream>>>(ei, ew, deg, counts);
  k_gnorm<<<48, 256, 0, stream>>>(ei, ew, deg, gnorm);
  k_scan<<<1, 64, 0, stream>>>(counts, offs, cursor);
  k_fill<<<48, 256, 0, stream>>>(ei, gnorm, cursor, csr_soff, csr_g, epack);
  k_wtr<<<240, 256, 0, stream>>>(W_t, WT);
  hipMemcpyAsync(h, x, (size_t)GN_ * 64 * sizeof(float), hipMemcpyDeviceToDevice, stream);

  for (int l = 0; l < 3; ++l){
    k_rowgemm<<<740, 256, 0, stream>>>(h, W_gcn + l * 4096, bufB);
    k_gcn_agg<<<2960, 256, 0, stream>>>(bufB, epack, offs, b_gcn + l * 64, bufC);
    k_rowgemm<<<740, 256, 0, stream>>>(bufC, W_gat + l * 4096, bufD);
    k_attn<<<740, 256, 0, stream>>>(bufD, att_s + l * 64, att_d + l * 64, asrc, adst);
    k_alpha<<<740, 256, 0, stream>>>(asrc, adst, csr_soff, offs, alpha, invden);
    k_gat_agg<<<2960, 256, 0, stream>>>(bufD, alpha, invden, csr_soff, offs,
                                        b_gat + l * 64, ln_g + l * 64, ln_b + l * 64, h);
  }

  k_tfuse<<<BN_, 64, 0, stream>>>(h, WT, b_t, bufD);

  dim3 g1(4, NKC_);
  k_mlp1<<<g1, 256, 0, stream>>>(bufD, W1, pbuf);
  k_red<<<128, 256, 0, stream>>>(pbuf, y1);
  k_mlp2<<<128, 64, 0, stream>>>(y1, b1, W2, b2, outp);
}

// Round 14
// 614.320 us; speedup vs baseline: 1.0906x; 1.0906x over previous
//
#include <hip/hip_runtime.h>
#include <hip/hip_bf16.h>

// Problem constants
#define B_   4
#define T_   32
#define N_   370
#define E_   11840
#define E2_  12210          // E_ + N_ self loops
#define H_   64
#define G_   128            // B_*T_
#define GN_  47360          // G_*N_
#define BN_  1480           // B_*N_
#define NH_  23680          // N_*H_
#define ECAP 320            // LDS edge-stage capacity per node (max deg ~70)
#define KC_  148            // mlp1 k-chunk (23680 = 148*160)
#define NKC_ 160            // number of k-chunks

__device__ __forceinline__ float gelu_f(float x){
  return 0.5f * x * (1.0f + erff(x * 0.7071067811865475f));
}
__device__ __forceinline__ float wsum64(float v){
  #pragma unroll
  for (int m = 32; m > 0; m >>= 1) v += __shfl_xor(v, m, 64);
  return v;
}
__device__ __forceinline__ float lrelu(float v){ return v > 0.f ? v : 0.2f * v; }

// ---------- edge preprocessing ----------
__global__ void k_deg_count(const int* __restrict__ ei, const float* __restrict__ ew,
                            float* __restrict__ deg, int* __restrict__ counts){
  int e = blockIdx.x * 256 + threadIdx.x;
  if (e >= E2_) return;
  int dst = (e < E_) ? ei[E_ + e] : (e - E_);
  float w = (e < E_) ? ew[e] : 1.0f;
  atomicAdd(&deg[dst], w);
  atomicAdd(&counts[dst], 1);
}

__global__ void k_gnorm(const int* __restrict__ ei, const float* __restrict__ ew,
                        const float* __restrict__ deg, float* __restrict__ gnorm){
  int e = blockIdx.x * 256 + threadIdx.x;
  if (e >= E2_) return;
  int s = (e < E_) ? ei[e] : (e - E_);
  int d = (e < E_) ? ei[E_ + e] : (e - E_);
  float w = (e < E_) ? ew[e] : 1.0f;
  float ds = deg[s] > 0.f ? rsqrtf(deg[s]) : 0.f;
  float dd = deg[d] > 0.f ? rsqrtf(deg[d]) : 0.f;
  gnorm[e] = ds * w * dd;
}

// wave-parallel exclusive scan over counts (one wave)
__global__ void k_scan(const int* __restrict__ counts, int* __restrict__ offs,
                       int* __restrict__ cursor){
  int lane = threadIdx.x;
  int run = 0;
  for (int c0 = 0; c0 < N_; c0 += 64){
    int n = c0 + lane;
    int v = (n < N_) ? counts[n] : 0;
    int s = v;
    #pragma unroll
    for (int m = 1; m < 64; m <<= 1){
      int t = __shfl_up(s, m, 64);
      if (lane >= m) s += t;
    }
    int excl = run + s - v;
    if (n < N_){ offs[n] = excl; cursor[n] = excl; }
    run += __shfl(s, 63, 64);
  }
  if (lane == 0) offs[N_] = run;
}

// stores PRE-SCALED source offset s*64 + packed (soff, gnorm) pairs
__global__ void k_fill(const int* __restrict__ ei, const float* __restrict__ gnorm,
                       int* __restrict__ cursor, int* __restrict__ csr_soff,
                       float* __restrict__ csr_g, int2* __restrict__ epack){
  int e = blockIdx.x * 256 + threadIdx.x;
  if (e >= E2_) return;
  int s = (e < E_) ? ei[e] : (e - E_);
  int d = (e < E_) ? ei[E_ + e] : (e - E_);
  int pos = atomicAdd(&cursor[d], 1);
  csr_soff[pos] = s * 64;
  float gw = gnorm[e];
  csr_g[pos] = gw;
  epack[pos] = make_int2(s * 64, __float_as_int(gw));
}

// transpose temporal-conv weights: WT[l][(ci*5+k)*64 + ho] = W_t[l][ho*320+ci*5+k]
__global__ void k_wtr(const float* __restrict__ Wt, float* __restrict__ WT){
  int i = blockIdx.x * 256 + threadIdx.x;     // 3*20480 exact
  int l = i / 20480, rem = i - l * 20480;
  int ho = rem / 320, j = rem - ho * 320;
  WT[l * 20480 + j * 64 + ho] = Wt[i];
}

// rows x 64 @ 64 x 64 -> rows x 64 ; 64 rows/block, 4x4 register tile
__global__ __launch_bounds__(256) void k_rowgemm(const float* __restrict__ in,
                                                 const float* __restrict__ W,
                                                 float* __restrict__ outp){
  __shared__ float Ws[64 * 64];     // [k][col]
  __shared__ float rsT[64 * 68];    // [k][row], padded
  int tid = threadIdx.x;
  size_t r0 = (size_t)blockIdx.x * 64;
  #pragma unroll
  for (int i = tid; i < 1024; i += 256)
    *(float4*)&Ws[i * 4] = *(const float4*)&W[i * 4];
  #pragma unroll
  for (int i = tid; i < 1024; i += 256){
    int r = i >> 4, k4 = (i & 15) * 4;
    float4 v = *(const float4*)&in[(r0 + r) * 64 + k4];
    rsT[(k4 + 0) * 68 + r] = v.x;
    rsT[(k4 + 1) * 68 + r] = v.y;
    rsT[(k4 + 2) * 68 + r] = v.z;
    rsT[(k4 + 3) * 68 + r] = v.w;
  }
  __syncthreads();
  int c0 = (tid & 15) * 4;
  int rr0 = (tid >> 4) * 4;
  float4 a0 = {0,0,0,0}, a1 = {0,0,0,0}, a2 = {0,0,0,0}, a3 = {0,0,0,0};
  #pragma unroll 4
  for (int k = 0; k < 64; ++k){
    float4 rv = *(const float4*)&rsT[k * 68 + rr0];
    float4 wv = *(const float4*)&Ws[k * 64 + c0];
    a0.x += rv.x*wv.x; a0.y += rv.x*wv.y; a0.z += rv.x*wv.z; a0.w += rv.x*wv.w;
    a1.x += rv.y*wv.x; a1.y += rv.y*wv.y; a1.z += rv.y*wv.z; a1.w += rv.y*wv.w;
    a2.x += rv.z*wv.x; a2.y += rv.z*wv.y; a2.z += rv.z*wv.z; a2.w += rv.z*wv.w;
    a3.x += rv.w*wv.x; a3.y += rv.w*wv.y; a3.z += rv.w*wv.z; a3.w += rv.w*wv.w;
  }
  *(float4*)&outp[(r0 + rr0 + 0) * 64 + c0] = a0;
  *(float4*)&outp[(r0 + rr0 + 1) * 64 + c0] = a1;
  *(float4*)&outp[(r0 + rr0 + 2) * 64 + c0] = a2;
  *(float4*)&outp[(r0 + rr0 + 3) * 64 + c0] = a3;
}

// rowgemm + fused attention scores (asrc/adst) for the GAT transform.
// Epilogue: per-head dot products reduced across 4 lanes via shfl_xor.
__global__ __launch_bounds__(256) void k_rowgemm_attn(const float* __restrict__ in,
    const float* __restrict__ W, float* __restrict__ outp,
    const float* __restrict__ att_s, const float* __restrict__ att_d,
    float* __restrict__ asrc, float* __restrict__ adst){
  __shared__ float Ws[64 * 64];
  __shared__ float rsT[64 * 68];
  int tid = threadIdx.x;
  size_t r0 = (size_t)blockIdx.x * 64;
  #pragma unroll
  for (int i = tid; i < 1024; i += 256)
    *(float4*)&Ws[i * 4] = *(const float4*)&W[i * 4];
  #pragma unroll
  for (int i = tid; i < 1024; i += 256){
    int r = i >> 4, k4 = (i & 15) * 4;
    float4 v = *(const float4*)&in[(r0 + r) * 64 + k4];
    rsT[(k4 + 0) * 68 + r] = v.x;
    rsT[(k4 + 1) * 68 + r] = v.y;
    rsT[(k4 + 2) * 68 + r] = v.z;
    rsT[(k4 + 3) * 68 + r] = v.w;
  }
  __syncthreads();
  int c0 = (tid & 15) * 4;
  int rr0 = (tid >> 4) * 4;
  float4 a0 = {0,0,0,0}, a1 = {0,0,0,0}, a2 = {0,0,0,0}, a3 = {0,0,0,0};
  #pragma unroll 4
  for (int k = 0; k < 64; ++k){
    float4 rv = *(const float4*)&rsT[k * 68 + rr0];
    float4 wv = *(const float4*)&Ws[k * 64 + c0];
    a0.x += rv.x*wv.x; a0.y += rv.x*wv.y; a0.z += rv.x*wv.z; a0.w += rv.x*wv.w;
    a1.x += rv.y*wv.x; a1.y += rv.y*wv.y; a1.z += rv.y*wv.z; a1.w += rv.y*wv.w;
    a2.x += rv.z*wv.x; a2.y += rv.z*wv.y; a2.z += rv.z*wv.z; a2.w += rv.z*wv.w;
    a3.x += rv.w*wv.x; a3.y += rv.w*wv.y; a3.z += rv.w*wv.z; a3.w += rv.w*wv.w;
  }
  *(float4*)&outp[(r0 + rr0 + 0) * 64 + c0] = a0;
  *(float4*)&outp[(r0 + rr0 + 1) * 64 + c0] = a1;
  *(float4*)&outp[(r0 + rr0 + 2) * 64 + c0] = a2;
  *(float4*)&outp[(r0 + rr0 + 3) * 64 + c0] = a3;
  // attention epilogue
  float4 as4 = *(const float4*)&att_s[c0];
  float4 ad4 = *(const float4*)&att_d[c0];
  float4 aq[4] = {a0, a1, a2, a3};
  float ps[4], pd[4];
  #pragma unroll
  for (int q = 0; q < 4; ++q){
    ps[q] = aq[q].x*as4.x + aq[q].y*as4.y + aq[q].z*as4.z + aq[q].w*as4.w;
    pd[q] = aq[q].x*ad4.x + aq[q].y*ad4.y + aq[q].z*ad4.z + aq[q].w*ad4.w;
  }
  #pragma unroll
  for (int q = 0; q < 4; ++q){
    ps[q] += __shfl_xor(ps[q], 1, 64); ps[q] += __shfl_xor(ps[q], 2, 64);
    pd[q] += __shfl_xor(pd[q], 1, 64); pd[q] += __shfl_xor(pd[q], 2, 64);
  }
  if ((tid & 3) == 0){
    int head = c0 >> 4;
    #pragma unroll
    for (int q = 0; q < 4; ++q){
      size_t row = r0 + rr0 + q;
      asrc[row * 4 + head] = ps[q];
      adst[row * 4 + head] = pd[q];
    }
  }
}

// GCN aggregate v4: block = (node n, group of 16 graphs); 4 graphs per wave.
__global__ __launch_bounds__(256) void k_gcn_agg(const float* __restrict__ hw,
    const int2* __restrict__ epack, const int* __restrict__ offs,
    const float* __restrict__ b_gcn, float* __restrict__ gout){
  __shared__ int2 eS[ECAP];
  int nb = blockIdx.x;              // 0..2959
  int n = nb % N_;
  int gg = nb / N_;                 // 0..7
  int tid = threadIdx.x;
  int o0 = offs[n], o1 = offs[n + 1];
  int deg = o1 - o0;
  int cap = deg < ECAP ? deg : ECAP;
  for (int i = tid; i < cap; i += 256) eS[i] = epack[o0 + i];
  __syncthreads();
  int wv = tid >> 6, c = tid & 63;
  int g0 = gg * 16 + wv * 4;
  const float* h0 = hw + (size_t)(g0 + 0) * NH_;
  const float* h1 = hw + (size_t)(g0 + 1) * NH_;
  const float* h2 = hw + (size_t)(g0 + 2) * NH_;
  const float* h3 = hw + (size_t)(g0 + 3) * NH_;
  float a0 = 0.f, a1 = 0.f, a2 = 0.f, a3 = 0.f;
  int p = 0;
  for (; p + 4 <= cap; p += 4){
    int2 ea = eS[p+0], eb = eS[p+1], ec = eS[p+2], ed = eS[p+3];
    float wa = __int_as_float(ea.y), wb = __int_as_float(eb.y);
    float wc = __int_as_float(ec.y), wd = __int_as_float(ed.y);
    float va0 = h0[ea.x+c], va1 = h1[ea.x+c], va2 = h2[ea.x+c], va3 = h3[ea.x+c];
    float vb0 = h0[eb.x+c], vb1 = h1[eb.x+c], vb2 = h2[eb.x+c], vb3 = h3[eb.x+c];
    float vc0 = h0[ec.x+c], vc1 = h1[ec.x+c], vc2 = h2[ec.x+c], vc3 = h3[ec.x+c];
    float vd0 = h0[ed.x+c], vd1 = h1[ed.x+c], vd2 = h2[ed.x+c], vd3 = h3[ed.x+c];
    a0 += wa*va0 + wb*vb0 + wc*vc0 + wd*vd0;
    a1 += wa*va1 + wb*vb1 + wc*vc1 + wd*vd1;
    a2 += wa*va2 + wb*vb2 + wc*vc2 + wd*vd2;
    a3 += wa*va3 + wb*vb3 + wc*vc3 + wd*vd3;
  }
  for (; p < cap; ++p){
    int2 e = eS[p];
    float w = __int_as_float(e.y);
    a0 += w * h0[e.x+c]; a1 += w * h1[e.x+c];
    a2 += w * h2[e.x+c]; a3 += w * h3[e.x+c];
  }
  for (int q = cap; q < deg; ++q){      // overflow fallback (not expected)
    int2 e = epack[o0 + q];
    float w = __int_as_float(e.y);
    a0 += w * h0[e.x+c]; a1 += w * h1[e.x+c];
    a2 += w * h2[e.x+c]; a3 += w * h3[e.x+c];
  }
  float bv = b_gcn[c];
  gout[((size_t)(g0+0) * N_ + n) * 64 + c] = gelu_f(a0 + bv);
  gout[((size_t)(g0+1) * N_ + n) * 64 + c] = gelu_f(a1 + bv);
  gout[((size_t)(g0+2) * N_ + n) * 64 + c] = gelu_f(a2 + bv);
  gout[((size_t)(g0+3) * N_ + n) * 64 + c] = gelu_f(a3 + bv);
}

// per (g,n,head): softmax max+denominator over incoming edges;
// writes UNNORMALIZED exp weights alpha[g][p][head] and invden[g][n][head]
__global__ void k_alpha(const float* __restrict__ asrc, const float* __restrict__ adst,
                        const int* __restrict__ csr_soff, const int* __restrict__ offs,
                        float* __restrict__ alpha, float* __restrict__ invden){
  int idx = blockIdx.x * 256 + threadIdx.x;   // (g*N+n)*4+head, GN_*4 exact
  int head = idx & 3;
  int gn = idx >> 2;
  int g = gn / N_, n = gn - g * N_;
  int o0 = offs[n], o1 = offs[n + 1];
  const float* as_g = asrc + (size_t)g * (N_ * 4);
  float adv = adst[idx];
  float m = -1e30f;
  int p = o0;
  for (; p + 4 <= o1; p += 4){
    int sa = csr_soff[p+0] >> 4, sb = csr_soff[p+1] >> 4;
    int sc = csr_soff[p+2] >> 4, sd = csr_soff[p+3] >> 4;
    float va = lrelu(as_g[sa + head] + adv);
    float vb = lrelu(as_g[sb + head] + adv);
    float vc = lrelu(as_g[sc + head] + adv);
    float vd = lrelu(as_g[sd + head] + adv);
    m = fmaxf(m, fmaxf(fmaxf(va, vb), fmaxf(vc, vd)));
  }
  for (; p < o1; ++p)
    m = fmaxf(m, lrelu(as_g[(csr_soff[p] >> 4) + head] + adv));
  float* al_g = alpha + (size_t)g * (E2_ * 4);
  float den = 0.f;
  p = o0;
  for (; p + 4 <= o1; p += 4){
    int sa = csr_soff[p+0] >> 4, sb = csr_soff[p+1] >> 4;
    int sc = csr_soff[p+2] >> 4, sd = csr_soff[p+3] >> 4;
    float ea = __expf(lrelu(as_g[sa + head] + adv) - m);
    float eb = __expf(lrelu(as_g[sb + head] + adv) - m);
    float ec = __expf(lrelu(as_g[sc + head] + adv) - m);
    float ed = __expf(lrelu(as_g[sd + head] + adv) - m);
    den += ea + eb + ec + ed;
    al_g[(p+0)*4 + head] = ea;
    al_g[(p+1)*4 + head] = eb;
    al_g[(p+2)*4 + head] = ec;
    al_g[(p+3)*4 + head] = ed;
  }
  for (; p < o1; ++p){
    float ex = __expf(lrelu(as_g[(csr_soff[p] >> 4) + head] + adv) - m);
    den += ex;
    al_g[p*4 + head] = ex;
  }
  invden[idx] = 1.f / den;
}

// GAT aggregate v4: block = (node n, group of 16 graphs); 4 graphs per wave.
__global__ __launch_bounds__(256) void k_gat_agg(const float* __restrict__ gh,
    const float* __restrict__ alpha, const float* __restrict__ invden,
    const int* __restrict__ csr_soff, const int* __restrict__ offs,
    const float* __restrict__ b_gat, const float* __restrict__ ln_g,
    const float* __restrict__ ln_b, float* __restrict__ h){
  __shared__ int sS[ECAP];
  int nb = blockIdx.x;
  int n = nb % N_;
  int gg = nb / N_;
  int tid = threadIdx.x;
  int o0 = offs[n], o1 = offs[n + 1];
  int deg = o1 - o0;
  int cap = deg < ECAP ? deg : ECAP;
  for (int i = tid; i < cap; i += 256) sS[i] = csr_soff[o0 + i];
  __syncthreads();
  int wv = tid >> 6, c = tid & 63;
  int g0 = gg * 16 + wv * 4;
  int head = c >> 4;
  const float* gp0 = gh + (size_t)(g0 + 0) * NH_;
  const float* gp1 = gh + (size_t)(g0 + 1) * NH_;
  const float* gp2 = gh + (size_t)(g0 + 2) * NH_;
  const float* gp3 = gh + (size_t)(g0 + 3) * NH_;
  const float* al0 = alpha + (size_t)(g0 + 0) * (E2_ * 4) + (size_t)o0 * 4 + head;
  const float* al1 = alpha + (size_t)(g0 + 1) * (E2_ * 4) + (size_t)o0 * 4 + head;
  const float* al2 = alpha + (size_t)(g0 + 2) * (E2_ * 4) + (size_t)o0 * 4 + head;
  const float* al3 = alpha + (size_t)(g0 + 3) * (E2_ * 4) + (size_t)o0 * 4 + head;
  float a0 = 0.f, a1 = 0.f, a2 = 0.f, a3 = 0.f;
  int p = 0;
  for (; p + 2 <= cap; p += 2){
    int s0 = sS[p], s1 = sS[p+1];
    float x00 = al0[(p+0)*4], x01 = al0[(p+1)*4];
    float x10 = al1[(p+0)*4], x11 = al1[(p+1)*4];
    float x20 = al2[(p+0)*4], x21 = al2[(p+1)*4];
    float x30 = al3[(p+0)*4], x31 = al3[(p+1)*4];
    float v00 = gp0[s0+c], v01 = gp0[s1+c];
    float v10 = gp1[s0+c], v11 = gp1[s1+c];
    float v20 = gp2[s0+c], v21 = gp2[s1+c];
    float v30 = gp3[s0+c], v31 = gp3[s1+c];
    a0 += x00*v00 + x01*v01;
    a1 += x10*v10 + x11*v11;
    a2 += x20*v20 + x21*v21;
    a3 += x30*v30 + x31*v31;
  }
  for (; p < cap; ++p){
    int s = sS[p];
    a0 += al0[p*4] * gp0[s+c];
    a1 += al1[p*4] * gp1[s+c];
    a2 += al2[p*4] * gp2[s+c];
    a3 += al3[p*4] * gp3[s+c];
  }
  for (int q = cap; q < deg; ++q){
    int s = csr_soff[o0 + q];
    a0 += al0[q*4] * gp0[s+c];
    a1 += al1[q*4] * gp1[s+c];
    a2 += al2[q*4] * gp2[s+c];
    a3 += al3[q*4] * gp3[s+c];
  }
  float bgv = b_gat[c], lgv = ln_g[c], lbv = ln_b[c];
  float accs[4] = {a0, a1, a2, a3};
  #pragma unroll
  for (int q = 0; q < 4; ++q){
    int gn = (g0 + q) * N_ + n;
    float outv = accs[q] * invden[(size_t)gn * 4 + head] + bgv;
    size_t hidx = (size_t)gn * 64 + c;
    float r = outv + h[hidx];
    float mu = wsum64(r) * (1.f / 64.f);
    float d = r - mu;
    float var = wsum64(d * d) * (1.f / 64.f);
    h[hidx] = d * rsqrtf(var + 1e-5f) * lgv + lbv;
  }
}

// Fused temporal v6 (= v4 + ci-unroll-2 software pipeline): 1 bn per block,
// 4 waves = (ciH 0/1) x (tH 0/1); ci-split partials reduced via LDS.
__global__ __launch_bounds__(256) void k_tfuse(const float* __restrict__ h,
    const float* __restrict__ WT, const float* __restrict__ bt,
    float* __restrict__ z){
  __shared__ float tile[64 * 36];        // padded x tile
  __shared__ float red[2][64 * 17];      // ciH=1 partials, [tH][ho*17+r]
  int tid = threadIdx.x;
  int wv = tid >> 6, lane = tid & 63;
  int ciH = wv & 1, tH = wv >> 1;
  int t0 = tH * 16;
  int bn = blockIdx.x;
  int b = bn / N_, n = bn - b * N_;
  for (int i = tid; i < 2304; i += 256) tile[i] = 0.f;
  __syncthreads();
  for (int i = tid; i < 2048; i += 256){
    int t = i >> 6, ch = i & 63;
    tile[ch * 36 + 2 + t] = h[((size_t)(b * T_ + t) * N_ + n) * 64 + ch];
  }
  __syncthreads();
  int ho = lane;
  int ci0 = ciH * 32;
  for (int l = 0; l < 3; ++l){
    const float* wl = WT + l * 20480 + ho;
    float bv = (ciH == 0) ? bt[l * 64 + ho] : 0.f;
    float acc[16];
    #pragma unroll
    for (int r = 0; r < 16; ++r) acc[r] = bv;
    for (int ci = ci0; ci < ci0 + 32; ci += 2){
      // front-load all W (global) and x (LDS) for two ci
      const float* wpA = wl + ci * 320;
      const float* wpB = wl + (ci + 1) * 320;
      float wA[5], wB[5];
      #pragma unroll
      for (int k = 0; k < 5; ++k){ wA[k] = wpA[k * 64]; wB[k] = wpB[k * 64]; }
      const float* xrA = &tile[ci * 36 + t0];
      const float* xrB = &tile[(ci + 1) * 36 + t0];
      float4 xa[5], xb[5];
      #pragma unroll
      for (int q = 0; q < 5; ++q){
        xa[q] = *(const float4*)&xrA[q * 4];
        xb[q] = *(const float4*)&xrB[q * 4];
      }
      float xwA[20], xwB[20];
      #pragma unroll
      for (int q = 0; q < 5; ++q){
        xwA[q*4+0] = xa[q].x; xwA[q*4+1] = xa[q].y; xwA[q*4+2] = xa[q].z; xwA[q*4+3] = xa[q].w;
        xwB[q*4+0] = xb[q].x; xwB[q*4+1] = xb[q].y; xwB[q*4+2] = xb[q].z; xwB[q*4+3] = xb[q].w;
      }
      #pragma unroll
      for (int k = 0; k < 5; ++k){
        #pragma unroll
        for (int r = 0; r < 16; ++r) acc[r] += xwA[r + k] * wA[k];
      }
      #pragma unroll
      for (int k = 0; k < 5; ++k){
        #pragma unroll
        for (int r = 0; r < 16; ++r) acc[r] += xwB[r + k] * wB[k];
      }
    }
    if (ciH == 1){
      #pragma unroll
      for (int r = 0; r < 16; ++r) red[tH][ho * 17 + r] = acc[r];
    }
    __syncthreads();      // partials in LDS; all tile reads done
    if (ciH == 0){
      #pragma unroll
      for (int r = 0; r < 16; ++r){
        int ti = t0 + r;
        float v = acc[r] + red[tH][ho * 17 + r];
        tile[ho * 36 + 2 + ti] = gelu_f(v) + tile[ho * 36 + 2 + ti];
      }
    }
    __syncthreads();      // tile updated before next layer
  }
  for (int i = tid; i < 2048; i += 256){
    int t = i >> 6, ch = i & 63;
    z[(size_t)(b * T_ + t) * NH_ + n * 64 + ch] = tile[ch * 36 + 2 + t];
  }
}

// MLP layer 1 (split-K, NO atomics): grid (4 b-groups, 160 kchunks of 148);
// each thread 8 rows x 4 cols; partials to private pbuf[kc] tile.
__global__ __launch_bounds__(256) void k_mlp1(const float* __restrict__ z,
    const float* __restrict__ W1, float* __restrict__ pbuf){
  __shared__ float zs[KC_ * 36];    // [j][r], r=0..31, stride 36
  int b = blockIdx.x;               // 0..3
  int kc = blockIdx.y;              // 0..159
  int base = kc * KC_;
  int tid = threadIdx.x;
  for (int i = tid; i < KC_ * 32; i += 256){
    int r = i / KC_, j = i - r * KC_;
    zs[j * 36 + r] = z[(size_t)(b * T_ + r) * NH_ + base + j];
  }
  __syncthreads();
  int r0 = (tid >> 6) * 8;
  int c0 = (tid & 63) * 4;
  float4 acc[8];
  #pragma unroll
  for (int r = 0; r < 8; ++r) acc[r] = (float4){0,0,0,0};
  const float* wbase = W1 + (size_t)base * 256 + c0;
  #pragma unroll 2
  for (int j = 0; j < KC_; ++j){
    float4 wv = *(const float4*)&wbase[(size_t)j * 256];
    float4 za = *(const float4*)&zs[j * 36 + r0];
    float4 zb = *(const float4*)&zs[j * 36 + r0 + 4];
    float zv[8] = {za.x, za.y, za.z, za.w, zb.x, zb.y, zb.z, zb.w};
    #pragma unroll
    for (int q = 0; q < 8; ++q){
      acc[q].x += zv[q]*wv.x; acc[q].y += zv[q]*wv.y;
      acc[q].z += zv[q]*wv.z; acc[q].w += zv[q]*wv.w;
    }
  }
  float* pb = pbuf + (size_t)kc * 32768;
  #pragma unroll
  for (int rr = 0; rr < 8; ++rr){
    int row = b * T_ + r0 + rr;
    *(float4*)&pb[(size_t)row * 256 + c0] = acc[rr];
  }
}

// reduce partials: y1[i] = sum_kc pbuf[kc*32768 + i]
__global__ __launch_bounds__(256) void k_red(const float* __restrict__ pbuf,
                                             float* __restrict__ y1){
  int i = blockIdx.x * 256 + threadIdx.x;   // 32768 exact
  float s0 = 0.f, s1 = 0.f, s2 = 0.f, s3 = 0.f;
  const float* p = pbuf + i;
  #pragma unroll 2
  for (int k = 0; k < NKC_; k += 4){
    s0 += p[(size_t)(k+0) * 32768];
    s1 += p[(size_t)(k+1) * 32768];
    s2 += p[(size_t)(k+2) * 32768];
    s3 += p[(size_t)(k+3) * 32768];
  }
  y1[i] = (s0 + s1) + (s2 + s3);
}

// MLP layer 2: out[128,64] = gelu(y1+b1) @ W2 + b2
__global__ __launch_bounds__(64) void k_mlp2(const float* __restrict__ y1,
    const float* __restrict__ b1, const float* __restrict__ W2,
    const float* __restrict__ b2, float* __restrict__ outp){
  __shared__ float a[256];
  int row = blockIdx.x, tid = threadIdx.x;
  for (int i = tid; i < 256; i += 64) a[i] = gelu_f(y1[(size_t)row * 256 + i] + b1[i]);
  __syncthreads();
  float acc = b2[tid];
  for (int i = 0; i < 256; ++i) acc += a[i] * W2[i * 64 + tid];
  outp[row * 64 + tid] = acc;
}

extern "C" void kernel_launch(void* const* d_in, const int* in_sizes, int n_in,
                              void* d_out, int out_size, void* d_ws, size_t ws_size,
                              hipStream_t stream){
  const float* x     = (const float*)d_in[0];
  const int*   ei    = (const int*)  d_in[1];
  const float* ew    = (const float*)d_in[2];
  const float* W_gcn = (const float*)d_in[3];
  const float* b_gcn = (const float*)d_in[4];
  const float* W_gat = (const float*)d_in[5];
  const float* att_s = (const float*)d_in[6];
  const float* att_d = (const float*)d_in[7];
  const float* b_gat = (const float*)d_in[8];
  const float* W_t   = (const float*)d_in[9];
  const float* b_t   = (const float*)d_in[10];
  const float* ln_g  = (const float*)d_in[11];
  const float* ln_b  = (const float*)d_in[12];
  const float* W1    = (const float*)d_in[13];
  const float* b1    = (const float*)d_in[14];
  const float* W2    = (const float*)d_in[15];
  const float* b2    = (const float*)d_in[16];
  float* outp = (float*)d_out;

  float* F = (float*)d_ws;
  size_t off = 0;
  float* deg    = F + off; off += 512;
  float* gnorm  = F + off; off += 12288;
  float* csr_g  = F + off; off += 12288;
  float* asrc   = F + off; off += 189440;
  float* adst   = F + off; off += 189440;
  float* invden = F + off; off += 189440;
  float* y1     = F + off; off += 32768;
  float* WT     = F + off; off += 61440;     // transposed temporal weights
  float* h      = F + off; off += 3031040;
  float* bufB   = F + off; off += 3031040;   // hw
  float* bufC   = F + off; off += 3031040;   // g
  float* bufD   = F + off; off += 3031040;   // gh / z
  float* alpha  = F + off; off += (size_t)G_ * E2_ * 4;   // 6,251,520 (reused as pbuf)
  float* pbuf   = alpha;                     // mlp1 partials: 160*32768 = 5,242,880 <= alpha
  int* I        = (int*)(F + off);
  int* counts   = I;
  int* offs     = I + 512;
  int* cursor   = I + 1024;
  int* csr_soff = I + 1536;                  // E2_ entries (12288 slot)
  int2* epack   = (int2*)(I + 13824);        // E2_ int2 entries

  hipMemsetAsync(deg, 0, 512 * sizeof(float), stream);
  hipMemsetAsync(counts, 0, 512 * sizeof(int), stream);

  k_deg_count<<<48, 256, 0, stream>>>(ei, ew, deg, counts);
  k_gnorm<<<48, 256, 0, stream>>>(ei, ew, deg, gnorm);
  k_scan<<<1, 64, 0, stream>>>(counts, offs, cursor);
  k_fill<<<48, 256, 0, stream>>>(ei, gnorm, cursor, csr_soff, csr_g, epack);
  k_wtr<<<240, 256, 0, stream>>>(W_t, WT);
  hipMemcpyAsync(h, x, (size_t)GN_ * 64 * sizeof(float), hipMemcpyDeviceToDevice, stream);

  for (int l = 0; l < 3; ++l){
    k_rowgemm<<<740, 256, 0, stream>>>(h, W_gcn + l * 4096, bufB);
    k_gcn_agg<<<2960, 256, 0, stream>>>(bufB, epack, offs, b_gcn + l * 64, bufC);
    k_rowgemm_attn<<<740, 256, 0, stream>>>(bufC, W_gat + l * 4096, bufD,
                                            att_s + l * 64, att_d + l * 64, asrc, adst);
    k_alpha<<<740, 256, 0, stream>>>(asrc, adst, csr_soff, offs, alpha, invden);
    k_gat_agg<<<2960, 256, 0, stream>>>(bufD, alpha, invden, csr_soff, offs,
                                        b_gat + l * 64, ln_g + l * 64, ln_b + l * 64, h);
  }

  k_tfuse<<<BN_, 256, 0, stream>>>(h, WT, b_t, bufD);

  dim3 g1(4, NKC_);
  k_mlp1<<<g1, 256, 0, stream>>>(bufD, W1, pbuf);
  k_red<<<128, 256, 0, stream>>>(pbuf, y1);
  k_mlp2<<<128, 64, 0, stream>>>(y1, b1, W2, b2, outp);
}

// Round 15
// 593.613 us; speedup vs baseline: 1.1286x; 1.0349x over previous
//
#include <hip/hip_runtime.h>
#include <hip/hip_bf16.h>

// Problem constants
#define B_   4
#define T_   32
#define N_   370
#define E_   11840
#define E2_  12210          // E_ + N_ self loops
#define H_   64
#define G_   128            // B_*T_
#define GN_  47360          // G_*N_
#define BN_  1480           // B_*N_
#define NH_  23680          // N_*H_
#define ECAP 320            // LDS edge-stage capacity per node (max deg ~70)
#define KC_  148            // mlp1 k-chunk (23680 = 148*160)
#define NKC_ 160            // number of k-chunks

typedef __hip_bfloat16 bf;

__device__ __forceinline__ float gelu_f(float x){
  return 0.5f * x * (1.0f + erff(x * 0.7071067811865475f));
}
__device__ __forceinline__ float wsum64(float v){
  #pragma unroll
  for (int m = 32; m > 0; m >>= 1) v += __shfl_xor(v, m, 64);
  return v;
}
__device__ __forceinline__ float lrelu(float v){ return v > 0.f ? v : 0.2f * v; }
__device__ __forceinline__ float b2f(bf x){ return __bfloat162float(x); }
__device__ __forceinline__ void store_bf4(bf* p, float4 v){
  bf tmp[4] = {__float2bfloat16(v.x), __float2bfloat16(v.y),
               __float2bfloat16(v.z), __float2bfloat16(v.w)};
  *(ushort4*)p = *(const ushort4*)tmp;
}

// ---------- edge preprocessing ----------
__global__ void k_deg_count(const int* __restrict__ ei, const float* __restrict__ ew,
                            float* __restrict__ deg, int* __restrict__ counts){
  int e = blockIdx.x * 256 + threadIdx.x;
  if (e >= E2_) return;
  int dst = (e < E_) ? ei[E_ + e] : (e - E_);
  float w = (e < E_) ? ew[e] : 1.0f;
  atomicAdd(&deg[dst], w);
  atomicAdd(&counts[dst], 1);
}

__global__ void k_gnorm(const int* __restrict__ ei, const float* __restrict__ ew,
                        const float* __restrict__ deg, float* __restrict__ gnorm){
  int e = blockIdx.x * 256 + threadIdx.x;
  if (e >= E2_) return;
  int s = (e < E_) ? ei[e] : (e - E_);
  int d = (e < E_) ? ei[E_ + e] : (e - E_);
  float w = (e < E_) ? ew[e] : 1.0f;
  float ds = deg[s] > 0.f ? rsqrtf(deg[s]) : 0.f;
  float dd = deg[d] > 0.f ? rsqrtf(deg[d]) : 0.f;
  gnorm[e] = ds * w * dd;
}

// wave-parallel exclusive scan over counts (one wave)
__global__ void k_scan(const int* __restrict__ counts, int* __restrict__ offs,
                       int* __restrict__ cursor){
  int lane = threadIdx.x;
  int run = 0;
  for (int c0 = 0; c0 < N_; c0 += 64){
    int n = c0 + lane;
    int v = (n < N_) ? counts[n] : 0;
    int s = v;
    #pragma unroll
    for (int m = 1; m < 64; m <<= 1){
      int t = __shfl_up(s, m, 64);
      if (lane >= m) s += t;
    }
    int excl = run + s - v;
    if (n < N_){ offs[n] = excl; cursor[n] = excl; }
    run += __shfl(s, 63, 64);
  }
  if (lane == 0) offs[N_] = run;
}

// stores PRE-SCALED source offset s*64 + packed (soff, gnorm) pairs
__global__ void k_fill(const int* __restrict__ ei, const float* __restrict__ gnorm,
                       int* __restrict__ cursor, int* __restrict__ csr_soff,
                       float* __restrict__ csr_g, int2* __restrict__ epack){
  int e = blockIdx.x * 256 + threadIdx.x;
  if (e >= E2_) return;
  int s = (e < E_) ? ei[e] : (e - E_);
  int d = (e < E_) ? ei[E_ + e] : (e - E_);
  int pos = atomicAdd(&cursor[d], 1);
  csr_soff[pos] = s * 64;
  float gw = gnorm[e];
  csr_g[pos] = gw;
  epack[pos] = make_int2(s * 64, __float_as_int(gw));
}

// transpose temporal-conv weights to bf16: WT[l][(ci*5+k)*64+ho]
__global__ void k_wtr(const float* __restrict__ Wt, bf* __restrict__ WT){
  int i = blockIdx.x * 256 + threadIdx.x;     // 3*20480 exact
  int l = i / 20480, rem = i - l * 20480;
  int ho = rem / 320, j = rem - ho * 320;
  WT[l * 20480 + j * 64 + ho] = __float2bfloat16(Wt[i]);
}

// rows x 64 @ 64 x 64 -> rows x 64 (bf16 out); 64 rows/block, 4x4 register tile
__global__ __launch_bounds__(256) void k_rowgemm(const float* __restrict__ in,
                                                 const float* __restrict__ W,
                                                 bf* __restrict__ outp){
  __shared__ float Ws[64 * 64];     // [k][col]
  __shared__ float rsT[64 * 68];    // [k][row], padded
  int tid = threadIdx.x;
  size_t r0 = (size_t)blockIdx.x * 64;
  #pragma unroll
  for (int i = tid; i < 1024; i += 256)
    *(float4*)&Ws[i * 4] = *(const float4*)&W[i * 4];
  #pragma unroll
  for (int i = tid; i < 1024; i += 256){
    int r = i >> 4, k4 = (i & 15) * 4;
    float4 v = *(const float4*)&in[(r0 + r) * 64 + k4];
    rsT[(k4 + 0) * 68 + r] = v.x;
    rsT[(k4 + 1) * 68 + r] = v.y;
    rsT[(k4 + 2) * 68 + r] = v.z;
    rsT[(k4 + 3) * 68 + r] = v.w;
  }
  __syncthreads();
  int c0 = (tid & 15) * 4;
  int rr0 = (tid >> 4) * 4;
  float4 a0 = {0,0,0,0}, a1 = {0,0,0,0}, a2 = {0,0,0,0}, a3 = {0,0,0,0};
  #pragma unroll 4
  for (int k = 0; k < 64; ++k){
    float4 rv = *(const float4*)&rsT[k * 68 + rr0];
    float4 wv = *(const float4*)&Ws[k * 64 + c0];
    a0.x += rv.x*wv.x; a0.y += rv.x*wv.y; a0.z += rv.x*wv.z; a0.w += rv.x*wv.w;
    a1.x += rv.y*wv.x; a1.y += rv.y*wv.y; a1.z += rv.y*wv.z; a1.w += rv.y*wv.w;
    a2.x += rv.z*wv.x; a2.y += rv.z*wv.y; a2.z += rv.z*wv.z; a2.w += rv.z*wv.w;
    a3.x += rv.w*wv.x; a3.y += rv.w*wv.y; a3.z += rv.w*wv.z; a3.w += rv.w*wv.w;
  }
  store_bf4(&outp[(r0 + rr0 + 0) * 64 + c0], a0);
  store_bf4(&outp[(r0 + rr0 + 1) * 64 + c0], a1);
  store_bf4(&outp[(r0 + rr0 + 2) * 64 + c0], a2);
  store_bf4(&outp[(r0 + rr0 + 3) * 64 + c0], a3);
}

// rowgemm + fused attention scores; bf16 output for the GAT gathers.
__global__ __launch_bounds__(256) void k_rowgemm_attn(const float* __restrict__ in,
    const float* __restrict__ W, bf* __restrict__ outp,
    const float* __restrict__ att_s, const float* __restrict__ att_d,
    float* __restrict__ asrc, float* __restrict__ adst){
  __shared__ float Ws[64 * 64];
  __shared__ float rsT[64 * 68];
  int tid = threadIdx.x;
  size_t r0 = (size_t)blockIdx.x * 64;
  #pragma unroll
  for (int i = tid; i < 1024; i += 256)
    *(float4*)&Ws[i * 4] = *(const float4*)&W[i * 4];
  #pragma unroll
  for (int i = tid; i < 1024; i += 256){
    int r = i >> 4, k4 = (i & 15) * 4;
    float4 v = *(const float4*)&in[(r0 + r) * 64 + k4];
    rsT[(k4 + 0) * 68 + r] = v.x;
    rsT[(k4 + 1) * 68 + r] = v.y;
    rsT[(k4 + 2) * 68 + r] = v.z;
    rsT[(k4 + 3) * 68 + r] = v.w;
  }
  __syncthreads();
  int c0 = (tid & 15) * 4;
  int rr0 = (tid >> 4) * 4;
  float4 a0 = {0,0,0,0}, a1 = {0,0,0,0}, a2 = {0,0,0,0}, a3 = {0,0,0,0};
  #pragma unroll 4
  for (int k = 0; k < 64; ++k){
    float4 rv = *(const float4*)&rsT[k * 68 + rr0];
    float4 wv = *(const float4*)&Ws[k * 64 + c0];
    a0.x += rv.x*wv.x; a0.y += rv.x*wv.y; a0.z += rv.x*wv.z; a0.w += rv.x*wv.w;
    a1.x += rv.y*wv.x; a1.y += rv.y*wv.y; a1.z += rv.y*wv.z; a1.w += rv.y*wv.w;
    a2.x += rv.z*wv.x; a2.y += rv.z*wv.y; a2.z += rv.z*wv.z; a2.w += rv.z*wv.w;
    a3.x += rv.w*wv.x; a3.y += rv.w*wv.y; a3.z += rv.w*wv.z; a3.w += rv.w*wv.w;
  }
  store_bf4(&outp[(r0 + rr0 + 0) * 64 + c0], a0);
  store_bf4(&outp[(r0 + rr0 + 1) * 64 + c0], a1);
  store_bf4(&outp[(r0 + rr0 + 2) * 64 + c0], a2);
  store_bf4(&outp[(r0 + rr0 + 3) * 64 + c0], a3);
  // attention epilogue (fp32 registers)
  float4 as4 = *(const float4*)&att_s[c0];
  float4 ad4 = *(const float4*)&att_d[c0];
  float4 aq[4] = {a0, a1, a2, a3};
  float ps[4], pd[4];
  #pragma unroll
  for (int q = 0; q < 4; ++q){
    ps[q] = aq[q].x*as4.x + aq[q].y*as4.y + aq[q].z*as4.z + aq[q].w*as4.w;
    pd[q] = aq[q].x*ad4.x + aq[q].y*ad4.y + aq[q].z*ad4.z + aq[q].w*ad4.w;
  }
  #pragma unroll
  for (int q = 0; q < 4; ++q){
    ps[q] += __shfl_xor(ps[q], 1, 64); ps[q] += __shfl_xor(ps[q], 2, 64);
    pd[q] += __shfl_xor(pd[q], 1, 64); pd[q] += __shfl_xor(pd[q], 2, 64);
  }
  if ((tid & 3) == 0){
    int head = c0 >> 4;
    #pragma unroll
    for (int q = 0; q < 4; ++q){
      size_t row = r0 + rr0 + q;
      asrc[row * 4 + head] = ps[q];
      adst[row * 4 + head] = pd[q];
    }
  }
}

// GCN aggregate: block = (node n, group of 16 graphs); 4 graphs per wave; bf16 gathers.
__global__ __launch_bounds__(256) void k_gcn_agg(const bf* __restrict__ hw,
    const int2* __restrict__ epack, const int* __restrict__ offs,
    const float* __restrict__ b_gcn, float* __restrict__ gout){
  __shared__ int2 eS[ECAP];
  int nb = blockIdx.x;              // 0..2959
  int n = nb % N_;
  int gg = nb / N_;                 // 0..7
  int tid = threadIdx.x;
  int o0 = offs[n], o1 = offs[n + 1];
  int deg = o1 - o0;
  int cap = deg < ECAP ? deg : ECAP;
  for (int i = tid; i < cap; i += 256) eS[i] = epack[o0 + i];
  __syncthreads();
  int wv = tid >> 6, c = tid & 63;
  int g0 = gg * 16 + wv * 4;
  const bf* h0 = hw + (size_t)(g0 + 0) * NH_;
  const bf* h1 = hw + (size_t)(g0 + 1) * NH_;
  const bf* h2 = hw + (size_t)(g0 + 2) * NH_;
  const bf* h3 = hw + (size_t)(g0 + 3) * NH_;
  float a0 = 0.f, a1 = 0.f, a2 = 0.f, a3 = 0.f;
  int p = 0;
  for (; p + 4 <= cap; p += 4){
    int2 ea = eS[p+0], eb = eS[p+1], ec = eS[p+2], ed = eS[p+3];
    float wa = __int_as_float(ea.y), wb = __int_as_float(eb.y);
    float wc = __int_as_float(ec.y), wd = __int_as_float(ed.y);
    float va0 = b2f(h0[ea.x+c]), va1 = b2f(h1[ea.x+c]), va2 = b2f(h2[ea.x+c]), va3 = b2f(h3[ea.x+c]);
    float vb0 = b2f(h0[eb.x+c]), vb1 = b2f(h1[eb.x+c]), vb2 = b2f(h2[eb.x+c]), vb3 = b2f(h3[eb.x+c]);
    float vc0 = b2f(h0[ec.x+c]), vc1 = b2f(h1[ec.x+c]), vc2 = b2f(h2[ec.x+c]), vc3 = b2f(h3[ec.x+c]);
    float vd0 = b2f(h0[ed.x+c]), vd1 = b2f(h1[ed.x+c]), vd2 = b2f(h2[ed.x+c]), vd3 = b2f(h3[ed.x+c]);
    a0 += wa*va0 + wb*vb0 + wc*vc0 + wd*vd0;
    a1 += wa*va1 + wb*vb1 + wc*vc1 + wd*vd1;
    a2 += wa*va2 + wb*vb2 + wc*vc2 + wd*vd2;
    a3 += wa*va3 + wb*vb3 + wc*vc3 + wd*vd3;
  }
  for (; p < cap; ++p){
    int2 e = eS[p];
    float w = __int_as_float(e.y);
    a0 += w * b2f(h0[e.x+c]); a1 += w * b2f(h1[e.x+c]);
    a2 += w * b2f(h2[e.x+c]); a3 += w * b2f(h3[e.x+c]);
  }
  for (int q = cap; q < deg; ++q){      // overflow fallback (not expected)
    int2 e = epack[o0 + q];
    float w = __int_as_float(e.y);
    a0 += w * b2f(h0[e.x+c]); a1 += w * b2f(h1[e.x+c]);
    a2 += w * b2f(h2[e.x+c]); a3 += w * b2f(h3[e.x+c]);
  }
  float bv = b_gcn[c];
  gout[((size_t)(g0+0) * N_ + n) * 64 + c] = gelu_f(a0 + bv);
  gout[((size_t)(g0+1) * N_ + n) * 64 + c] = gelu_f(a1 + bv);
  gout[((size_t)(g0+2) * N_ + n) * 64 + c] = gelu_f(a2 + bv);
  gout[((size_t)(g0+3) * N_ + n) * 64 + c] = gelu_f(a3 + bv);
}

// per (g,n,head): softmax max+denominator; writes UNNORMALIZED bf16 exp weights
__global__ void k_alpha(const float* __restrict__ asrc, const float* __restrict__ adst,
                        const int* __restrict__ csr_soff, const int* __restrict__ offs,
                        bf* __restrict__ alpha, float* __restrict__ invden){
  int idx = blockIdx.x * 256 + threadIdx.x;   // (g*N+n)*4+head, GN_*4 exact
  int head = idx & 3;
  int gn = idx >> 2;
  int g = gn / N_, n = gn - g * N_;
  int o0 = offs[n], o1 = offs[n + 1];
  const float* as_g = asrc + (size_t)g * (N_ * 4);
  float adv = adst[idx];
  float m = -1e30f;
  int p = o0;
  for (; p + 4 <= o1; p += 4){
    int sa = csr_soff[p+0] >> 4, sb = csr_soff[p+1] >> 4;
    int sc = csr_soff[p+2] >> 4, sd = csr_soff[p+3] >> 4;
    float va = lrelu(as_g[sa + head] + adv);
    float vb = lrelu(as_g[sb + head] + adv);
    float vc = lrelu(as_g[sc + head] + adv);
    float vd = lrelu(as_g[sd + head] + adv);
    m = fmaxf(m, fmaxf(fmaxf(va, vb), fmaxf(vc, vd)));
  }
  for (; p < o1; ++p)
    m = fmaxf(m, lrelu(as_g[(csr_soff[p] >> 4) + head] + adv));
  bf* al_g = alpha + (size_t)g * (E2_ * 4);
  float den = 0.f;
  p = o0;
  for (; p + 4 <= o1; p += 4){
    int sa = csr_soff[p+0] >> 4, sb = csr_soff[p+1] >> 4;
    int sc = csr_soff[p+2] >> 4, sd = csr_soff[p+3] >> 4;
    float ea = __expf(lrelu(as_g[sa + head] + adv) - m);
    float eb = __expf(lrelu(as_g[sb + head] + adv) - m);
    float ec = __expf(lrelu(as_g[sc + head] + adv) - m);
    float ed = __expf(lrelu(as_g[sd + head] + adv) - m);
    den += ea + eb + ec + ed;
    al_g[(p+0)*4 + head] = __float2bfloat16(ea);
    al_g[(p+1)*4 + head] = __float2bfloat16(eb);
    al_g[(p+2)*4 + head] = __float2bfloat16(ec);
    al_g[(p+3)*4 + head] = __float2bfloat16(ed);
  }
  for (; p < o1; ++p){
    float ex = __expf(lrelu(as_g[(csr_soff[p] >> 4) + head] + adv) - m);
    den += ex;
    al_g[p*4 + head] = __float2bfloat16(ex);
  }
  invden[idx] = 1.f / den;
}

// GAT aggregate: block = (node n, group of 16 graphs); 4 graphs/wave; bf16 gathers.
__global__ __launch_bounds__(256) void k_gat_agg(const bf* __restrict__ gh,
    const bf* __restrict__ alpha, const float* __restrict__ invden,
    const int* __restrict__ csr_soff, const int* __restrict__ offs,
    const float* __restrict__ b_gat, const float* __restrict__ ln_g,
    const float* __restrict__ ln_b, float* __restrict__ h){
  __shared__ int sS[ECAP];
  int nb = blockIdx.x;
  int n = nb % N_;
  int gg = nb / N_;
  int tid = threadIdx.x;
  int o0 = offs[n], o1 = offs[n + 1];
  int deg = o1 - o0;
  int cap = deg < ECAP ? deg : ECAP;
  for (int i = tid; i < cap; i += 256) sS[i] = csr_soff[o0 + i];
  __syncthreads();
  int wv = tid >> 6, c = tid & 63;
  int g0 = gg * 16 + wv * 4;
  int head = c >> 4;
  const bf* gp0 = gh + (size_t)(g0 + 0) * NH_;
  const bf* gp1 = gh + (size_t)(g0 + 1) * NH_;
  const bf* gp2 = gh + (size_t)(g0 + 2) * NH_;
  const bf* gp3 = gh + (size_t)(g0 + 3) * NH_;
  const bf* al0 = alpha + (size_t)(g0 + 0) * (E2_ * 4) + (size_t)o0 * 4 + head;
  const bf* al1 = alpha + (size_t)(g0 + 1) * (E2_ * 4) + (size_t)o0 * 4 + head;
  const bf* al2 = alpha + (size_t)(g0 + 2) * (E2_ * 4) + (size_t)o0 * 4 + head;
  const bf* al3 = alpha + (size_t)(g0 + 3) * (E2_ * 4) + (size_t)o0 * 4 + head;
  float a0 = 0.f, a1 = 0.f, a2 = 0.f, a3 = 0.f;
  int p = 0;
  for (; p + 2 <= cap; p += 2){
    int s0 = sS[p], s1 = sS[p+1];
    float x00 = b2f(al0[(p+0)*4]), x01 = b2f(al0[(p+1)*4]);
    float x10 = b2f(al1[(p+0)*4]), x11 = b2f(al1[(p+1)*4]);
    float x20 = b2f(al2[(p+0)*4]), x21 = b2f(al2[(p+1)*4]);
    float x30 = b2f(al3[(p+0)*4]), x31 = b2f(al3[(p+1)*4]);
    float v00 = b2f(gp0[s0+c]), v01 = b2f(gp0[s1+c]);
    float v10 = b2f(gp1[s0+c]), v11 = b2f(gp1[s1+c]);
    float v20 = b2f(gp2[s0+c]), v21 = b2f(gp2[s1+c]);
    float v30 = b2f(gp3[s0+c]), v31 = b2f(gp3[s1+c]);
    a0 += x00*v00 + x01*v01;
    a1 += x10*v10 + x11*v11;
    a2 += x20*v20 + x21*v21;
    a3 += x30*v30 + x31*v31;
  }
  for (; p < cap; ++p){
    int s = sS[p];
    a0 += b2f(al0[p*4]) * b2f(gp0[s+c]);
    a1 += b2f(al1[p*4]) * b2f(gp1[s+c]);
    a2 += b2f(al2[p*4]) * b2f(gp2[s+c]);
    a3 += b2f(al3[p*4]) * b2f(gp3[s+c]);
  }
  for (int q = cap; q < deg; ++q){
    int s = csr_soff[o0 + q];
    a0 += b2f(al0[q*4]) * b2f(gp0[s+c]);
    a1 += b2f(al1[q*4]) * b2f(gp1[s+c]);
    a2 += b2f(al2[q*4]) * b2f(gp2[s+c]);
    a3 += b2f(al3[q*4]) * b2f(gp3[s+c]);
  }
  float bgv = b_gat[c], lgv = ln_g[c], lbv = ln_b[c];
  float accs[4] = {a0, a1, a2, a3};
  #pragma unroll
  for (int q = 0; q < 4; ++q){
    int gn = (g0 + q) * N_ + n;
    float outv = accs[q] * invden[(size_t)gn * 4 + head] + bgv;
    size_t hidx = (size_t)gn * 64 + c;
    float r = outv + h[hidx];
    float mu = wsum64(r) * (1.f / 64.f);
    float d = r - mu;
    float var = wsum64(d * d) * (1.f / 64.f);
    h[hidx] = d * rsqrtf(var + 1e-5f) * lgv + lbv;
  }
}

// Fused temporal: 1 bn per block, 4 waves = (ciH 0/1) x (tH 0/1);
// bf16 W loads (40 KB/layer, ~L1-resident); ci-split partials via LDS.
__global__ __launch_bounds__(256) void k_tfuse(const float* __restrict__ h,
    const bf* __restrict__ WT, const float* __restrict__ bt,
    float* __restrict__ z){
  __shared__ float tile[64 * 36];        // padded x tile
  __shared__ float red[2][64 * 17];      // ciH=1 partials, [tH][ho*17+r]
  int tid = threadIdx.x;
  int wv = tid >> 6, lane = tid & 63;
  int ciH = wv & 1, tH = wv >> 1;
  int t0 = tH * 16;
  int bn = blockIdx.x;
  int b = bn / N_, n = bn - b * N_;
  for (int i = tid; i < 2304; i += 256) tile[i] = 0.f;
  __syncthreads();
  for (int i = tid; i < 2048; i += 256){
    int t = i >> 6, ch = i & 63;
    tile[ch * 36 + 2 + t] = h[((size_t)(b * T_ + t) * N_ + n) * 64 + ch];
  }
  __syncthreads();
  int ho = lane;
  int ci0 = ciH * 32;
  for (int l = 0; l < 3; ++l){
    const bf* wl = WT + l * 20480 + ho;
    float bv = (ciH == 0) ? bt[l * 64 + ho] : 0.f;
    float acc[16];
    #pragma unroll
    for (int r = 0; r < 16; ++r) acc[r] = bv;
    for (int ci = ci0; ci < ci0 + 32; ci += 2){
      const bf* wpA = wl + ci * 320;
      const bf* wpB = wl + (ci + 1) * 320;
      float wA[5], wB[5];
      #pragma unroll
      for (int k = 0; k < 5; ++k){ wA[k] = b2f(wpA[k * 64]); wB[k] = b2f(wpB[k * 64]); }
      const float* xrA = &tile[ci * 36 + t0];
      const float* xrB = &tile[(ci + 1) * 36 + t0];
      float4 xa[5], xb[5];
      #pragma unroll
      for (int q = 0; q < 5; ++q){
        xa[q] = *(const float4*)&xrA[q * 4];
        xb[q] = *(const float4*)&xrB[q * 4];
      }
      float xwA[20], xwB[20];
      #pragma unroll
      for (int q = 0; q < 5; ++q){
        xwA[q*4+0] = xa[q].x; xwA[q*4+1] = xa[q].y; xwA[q*4+2] = xa[q].z; xwA[q*4+3] = xa[q].w;
        xwB[q*4+0] = xb[q].x; xwB[q*4+1] = xb[q].y; xwB[q*4+2] = xb[q].z; xwB[q*4+3] = xb[q].w;
      }
      #pragma unroll
      for (int k = 0; k < 5; ++k){
        #pragma unroll
        for (int r = 0; r < 16; ++r) acc[r] += xwA[r + k] * wA[k];
      }
      #pragma unroll
      for (int k = 0; k < 5; ++k){
        #pragma unroll
        for (int r = 0; r < 16; ++r) acc[r] += xwB[r + k] * wB[k];
      }
    }
    if (ciH == 1){
      #pragma unroll
      for (int r = 0; r < 16; ++r) red[tH][ho * 17 + r] = acc[r];
    }
    __syncthreads();
    if (ciH == 0){
      #pragma unroll
      for (int r = 0; r < 16; ++r){
        int ti = t0 + r;
        float v = acc[r] + red[tH][ho * 17 + r];
        tile[ho * 36 + 2 + ti] = gelu_f(v) + tile[ho * 36 + 2 + ti];
      }
    }
    __syncthreads();
  }
  for (int i = tid; i < 2048; i += 256){
    int t = i >> 6, ch = i & 63;
    z[(size_t)(b * T_ + t) * NH_ + n * 64 + ch] = tile[ch * 36 + 2 + t];
  }
}

// MLP layer 1 (split-K, NO atomics): grid (4 b-groups, 160 kchunks of 148)
__global__ __launch_bounds__(256) void k_mlp1(const float* __restrict__ z,
    const float* __restrict__ W1, float* __restrict__ pbuf){
  __shared__ float zs[KC_ * 36];    // [j][r], r=0..31, stride 36
  int b = blockIdx.x;               // 0..3
  int kc = blockIdx.y;              // 0..159
  int base = kc * KC_;
  int tid = threadIdx.x;
  for (int i = tid; i < KC_ * 32; i += 256){
    int r = i / KC_, j = i - r * KC_;
    zs[j * 36 + r] = z[(size_t)(b * T_ + r) * NH_ + base + j];
  }
  __syncthreads();
  int r0 = (tid >> 6) * 8;
  int c0 = (tid & 63) * 4;
  float4 acc[8];
  #pragma unroll
  for (int r = 0; r < 8; ++r) acc[r] = (float4){0,0,0,0};
  const float* wbase = W1 + (size_t)base * 256 + c0;
  #pragma unroll 2
  for (int j = 0; j < KC_; ++j){
    float4 wv = *(const float4*)&wbase[(size_t)j * 256];
    float4 za = *(const float4*)&zs[j * 36 + r0];
    float4 zb = *(const float4*)&zs[j * 36 + r0 + 4];
    float zv[8] = {za.x, za.y, za.z, za.w, zb.x, zb.y, zb.z, zb.w};
    #pragma unroll
    for (int q = 0; q < 8; ++q){
      acc[q].x += zv[q]*wv.x; acc[q].y += zv[q]*wv.y;
      acc[q].z += zv[q]*wv.z; acc[q].w += zv[q]*wv.w;
    }
  }
  float* pb = pbuf + (size_t)kc * 32768;
  #pragma unroll
  for (int rr = 0; rr < 8; ++rr){
    int row = b * T_ + r0 + rr;
    *(float4*)&pb[(size_t)row * 256 + c0] = acc[rr];
  }
}

// reduce partials: y1[i] = sum_kc pbuf[kc*32768 + i]
__global__ __launch_bounds__(256) void k_red(const float* __restrict__ pbuf,
                                             float* __restrict__ y1){
  int i = blockIdx.x * 256 + threadIdx.x;   // 32768 exact
  float s0 = 0.f, s1 = 0.f, s2 = 0.f, s3 = 0.f;
  const float* p = pbuf + i;
  #pragma unroll 2
  for (int k = 0; k < NKC_; k += 4){
    s0 += p[(size_t)(k+0) * 32768];
    s1 += p[(size_t)(k+1) * 32768];
    s2 += p[(size_t)(k+2) * 32768];
    s3 += p[(size_t)(k+3) * 32768];
  }
  y1[i] = (s0 + s1) + (s2 + s3);
}

// MLP layer 2: out[128,64] = gelu(y1+b1) @ W2 + b2
__global__ __launch_bounds__(64) void k_mlp2(const float* __restrict__ y1,
    const float* __restrict__ b1, const float* __restrict__ W2,
    const float* __restrict__ b2, float* __restrict__ outp){
  __shared__ float a[256];
  int row = blockIdx.x, tid = threadIdx.x;
  for (int i = tid; i < 256; i += 64) a[i] = gelu_f(y1[(size_t)row * 256 + i] + b1[i]);
  __syncthreads();
  float acc = b2[tid];
  for (int i = 0; i < 256; ++i) acc += a[i] * W2[i * 64 + tid];
  outp[row * 64 + tid] = acc;
}

extern "C" void kernel_launch(void* const* d_in, const int* in_sizes, int n_in,
                              void* d_out, int out_size, void* d_ws, size_t ws_size,
                              hipStream_t stream){
  const float* x     = (const float*)d_in[0];
  const int*   ei    = (const int*)  d_in[1];
  const float* ew    = (const float*)d_in[2];
  const float* W_gcn = (const float*)d_in[3];
  const float* b_gcn = (const float*)d_in[4];
  const float* W_gat = (const float*)d_in[5];
  const float* att_s = (const float*)d_in[6];
  const float* att_d = (const float*)d_in[7];
  const float* b_gat = (const float*)d_in[8];
  const float* W_t   = (const float*)d_in[9];
  const float* b_t   = (const float*)d_in[10];
  const float* ln_g  = (const float*)d_in[11];
  const float* ln_b  = (const float*)d_in[12];
  const float* W1    = (const float*)d_in[13];
  const float* b1    = (const float*)d_in[14];
  const float* W2    = (const float*)d_in[15];
  const float* b2    = (const float*)d_in[16];
  float* outp = (float*)d_out;

  float* F = (float*)d_ws;
  size_t off = 0;
  float* deg    = F + off; off += 512;
  float* gnorm  = F + off; off += 12288;
  float* csr_g  = F + off; off += 12288;
  float* asrc   = F + off; off += 189440;
  float* adst   = F + off; off += 189440;
  float* invden = F + off; off += 189440;
  float* y1     = F + off; off += 32768;
  float* WTf    = F + off; off += 61440;     // bf16 transposed temporal weights (slot in floats)
  float* h      = F + off; off += 3031040;
  float* bufB   = F + off; off += 3031040;   // hw (bf16, slot in floats)
  float* bufC   = F + off; off += 3031040;   // g (fp32)
  float* bufD   = F + off; off += 3031040;   // gh (bf16) / z (fp32)
  float* alphaf = F + off; off += (size_t)G_ * E2_ * 4;   // alpha (bf16) / pbuf (fp32)
  float* pbuf   = alphaf;                    // mlp1 partials: 160*32768 floats <= slot
  int* I        = (int*)(F + off);
  int* counts   = I;
  int* offs     = I + 512;
  int* cursor   = I + 1024;
  int* csr_soff = I + 1536;                  // E2_ entries (12288 slot)
  int2* epack   = (int2*)(I + 13824);        // E2_ int2 entries

  bf* WT     = (bf*)WTf;
  bf* hw16   = (bf*)bufB;
  bf* gh16   = (bf*)bufD;
  bf* alpha16= (bf*)alphaf;

  hipMemsetAsync(deg, 0, 512 * sizeof(float), stream);
  hipMemsetAsync(counts, 0, 512 * sizeof(int), stream);

  k_deg_count<<<48, 256, 0, stream>>>(ei, ew, deg, counts);
  k_gnorm<<<48, 256, 0, stream>>>(ei, ew, deg, gnorm);
  k_scan<<<1, 64, 0, stream>>>(counts, offs, cursor);
  k_fill<<<48, 256, 0, stream>>>(ei, gnorm, cursor, csr_soff, csr_g, epack);
  k_wtr<<<240, 256, 0, stream>>>(W_t, WT);
  hipMemcpyAsync(h, x, (size_t)GN_ * 64 * sizeof(float), hipMemcpyDeviceToDevice, stream);

  for (int l = 0; l < 3; ++l){
    k_rowgemm<<<740, 256, 0, stream>>>(h, W_gcn + l * 4096, hw16);
    k_gcn_agg<<<2960, 256, 0, stream>>>(hw16, epack, offs, b_gcn + l * 64, bufC);
    k_rowgemm_attn<<<740, 256, 0, stream>>>(bufC, W_gat + l * 4096, gh16,
                                            att_s + l * 64, att_d + l * 64, asrc, adst);
    k_alpha<<<740, 256, 0, stream>>>(asrc, adst, csr_soff, offs, alpha16, invden);
    k_gat_agg<<<2960, 256, 0, stream>>>(gh16, alpha16, invden, csr_soff, offs,
                                        b_gat + l * 64, ln_g + l * 64, ln_b + l * 64, h);
  }

  k_tfuse<<<BN_, 256, 0, stream>>>(h, WT, b_t, bufD);

  dim3 g1(4, NKC_);
  k_mlp1<<<g1, 256, 0, stream>>>(bufD, W1, pbuf);
  k_red<<<128, 256, 0, stream>>>(pbuf, y1);
  k_mlp2<<<128, 64, 0, stream>>>(y1, b1, W2, b2, outp);
}

// Round 16
// 584.599 us; speedup vs baseline: 1.1460x; 1.0154x over previous
//
#include <hip/hip_runtime.h>
#include <hip/hip_bf16.h>

// Problem constants
#define B_   4
#define T_   32
#define N_   370
#define E_   11840
#define E2_  12210          // E_ + N_ self loops
#define H_   64
#define G_   128            // B_*T_
#define GN_  47360          // G_*N_
#define BN_  1480           // B_*N_
#define NH_  23680          // N_*H_
#define ECAP 320            // LDS edge-stage capacity per node (max deg ~70)
#define KC_  148            // mlp1 k-chunk (23680 = 148*160)
#define NKC_ 160            // number of k-chunks

typedef __hip_bfloat16 bf;

__device__ __forceinline__ float gelu_f(float x){
  return 0.5f * x * (1.0f + erff(x * 0.7071067811865475f));
}
__device__ __forceinline__ float wsum64(float v){
  #pragma unroll
  for (int m = 32; m > 0; m >>= 1) v += __shfl_xor(v, m, 64);
  return v;
}
__device__ __forceinline__ float lrelu(float v){ return v > 0.f ? v : 0.2f * v; }
__device__ __forceinline__ float b2f(bf x){ return __bfloat162float(x); }
__device__ __forceinline__ void store_bf4(bf* p, float4 v){
  bf tmp[4] = {__float2bfloat16(v.x), __float2bfloat16(v.y),
               __float2bfloat16(v.z), __float2bfloat16(v.w)};
  *(ushort4*)p = *(const ushort4*)tmp;
}

// ---------- edge preprocessing ----------
__global__ void k_deg_count(const int* __restrict__ ei, const float* __restrict__ ew,
                            float* __restrict__ deg, int* __restrict__ counts){
  int e = blockIdx.x * 256 + threadIdx.x;
  if (e >= E2_) return;
  int dst = (e < E_) ? ei[E_ + e] : (e - E_);
  float w = (e < E_) ? ew[e] : 1.0f;
  atomicAdd(&deg[dst], w);
  atomicAdd(&counts[dst], 1);
}

__global__ void k_gnorm(const int* __restrict__ ei, const float* __restrict__ ew,
                        const float* __restrict__ deg, float* __restrict__ gnorm){
  int e = blockIdx.x * 256 + threadIdx.x;
  if (e >= E2_) return;
  int s = (e < E_) ? ei[e] : (e - E_);
  int d = (e < E_) ? ei[E_ + e] : (e - E_);
  float w = (e < E_) ? ew[e] : 1.0f;
  float ds = deg[s] > 0.f ? rsqrtf(deg[s]) : 0.f;
  float dd = deg[d] > 0.f ? rsqrtf(deg[d]) : 0.f;
  gnorm[e] = ds * w * dd;
}

// wave-parallel exclusive scan over counts (one wave)
__global__ void k_scan(const int* __restrict__ counts, int* __restrict__ offs,
                       int* __restrict__ cursor){
  int lane = threadIdx.x;
  int run = 0;
  for (int c0 = 0; c0 < N_; c0 += 64){
    int n = c0 + lane;
    int v = (n < N_) ? counts[n] : 0;
    int s = v;
    #pragma unroll
    for (int m = 1; m < 64; m <<= 1){
      int t = __shfl_up(s, m, 64);
      if (lane >= m) s += t;
    }
    int excl = run + s - v;
    if (n < N_){ offs[n] = excl; cursor[n] = excl; }
    run += __shfl(s, 63, 64);
  }
  if (lane == 0) offs[N_] = run;
}

// stores PRE-SCALED source offset s*64 + packed (soff, gnorm) pairs
__global__ void k_fill(const int* __restrict__ ei, const float* __restrict__ gnorm,
                       int* __restrict__ cursor, int* __restrict__ csr_soff,
                       float* __restrict__ csr_g, int2* __restrict__ epack){
  int e = blockIdx.x * 256 + threadIdx.x;
  if (e >= E2_) return;
  int s = (e < E_) ? ei[e] : (e - E_);
  int d = (e < E_) ? ei[E_ + e] : (e - E_);
  int pos = atomicAdd(&cursor[d], 1);
  csr_soff[pos] = s * 64;
  float gw = gnorm[e];
  csr_g[pos] = gw;
  epack[pos] = make_int2(s * 64, __float_as_int(gw));
}

// transpose temporal-conv weights to bf16: WT[l][(ci*5+k)*64+ho]
__global__ void k_wtr(const float* __restrict__ Wt, bf* __restrict__ WT){
  int i = blockIdx.x * 256 + threadIdx.x;     // 3*20480 exact
  int l = i / 20480, rem = i - l * 20480;
  int ho = rem / 320, j = rem - ho * 320;
  WT[l * 20480 + j * 64 + ho] = __float2bfloat16(Wt[i]);
}

// rows x 64 @ 64 x 64 -> rows x 64 (bf16 out); 64 rows/block, 4x4 register tile
__global__ __launch_bounds__(256) void k_rowgemm(const float* __restrict__ in,
                                                 const float* __restrict__ W,
                                                 bf* __restrict__ outp){
  __shared__ float Ws[64 * 64];     // [k][col]
  __shared__ float rsT[64 * 68];    // [k][row], padded
  int tid = threadIdx.x;
  size_t r0 = (size_t)blockIdx.x * 64;
  #pragma unroll
  for (int i = tid; i < 1024; i += 256)
    *(float4*)&Ws[i * 4] = *(const float4*)&W[i * 4];
  #pragma unroll
  for (int i = tid; i < 1024; i += 256){
    int r = i >> 4, k4 = (i & 15) * 4;
    float4 v = *(const float4*)&in[(r0 + r) * 64 + k4];
    rsT[(k4 + 0) * 68 + r] = v.x;
    rsT[(k4 + 1) * 68 + r] = v.y;
    rsT[(k4 + 2) * 68 + r] = v.z;
    rsT[(k4 + 3) * 68 + r] = v.w;
  }
  __syncthreads();
  int c0 = (tid & 15) * 4;
  int rr0 = (tid >> 4) * 4;
  float4 a0 = {0,0,0,0}, a1 = {0,0,0,0}, a2 = {0,0,0,0}, a3 = {0,0,0,0};
  #pragma unroll 4
  for (int k = 0; k < 64; ++k){
    float4 rv = *(const float4*)&rsT[k * 68 + rr0];
    float4 wv = *(const float4*)&Ws[k * 64 + c0];
    a0.x += rv.x*wv.x; a0.y += rv.x*wv.y; a0.z += rv.x*wv.z; a0.w += rv.x*wv.w;
    a1.x += rv.y*wv.x; a1.y += rv.y*wv.y; a1.z += rv.y*wv.z; a1.w += rv.y*wv.w;
    a2.x += rv.z*wv.x; a2.y += rv.z*wv.y; a2.z += rv.z*wv.z; a2.w += rv.z*wv.w;
    a3.x += rv.w*wv.x; a3.y += rv.w*wv.y; a3.z += rv.w*wv.z; a3.w += rv.w*wv.w;
  }
  store_bf4(&outp[(r0 + rr0 + 0) * 64 + c0], a0);
  store_bf4(&outp[(r0 + rr0 + 1) * 64 + c0], a1);
  store_bf4(&outp[(r0 + rr0 + 2) * 64 + c0], a2);
  store_bf4(&outp[(r0 + rr0 + 3) * 64 + c0], a3);
}

// rowgemm + fused attention scores; bf16 output for the GAT gathers.
__global__ __launch_bounds__(256) void k_rowgemm_attn(const float* __restrict__ in,
    const float* __restrict__ W, bf* __restrict__ outp,
    const float* __restrict__ att_s, const float* __restrict__ att_d,
    float* __restrict__ asrc, float* __restrict__ adst){
  __shared__ float Ws[64 * 64];
  __shared__ float rsT[64 * 68];
  int tid = threadIdx.x;
  size_t r0 = (size_t)blockIdx.x * 64;
  #pragma unroll
  for (int i = tid; i < 1024; i += 256)
    *(float4*)&Ws[i * 4] = *(const float4*)&W[i * 4];
  #pragma unroll
  for (int i = tid; i < 1024; i += 256){
    int r = i >> 4, k4 = (i & 15) * 4;
    float4 v = *(const float4*)&in[(r0 + r) * 64 + k4];
    rsT[(k4 + 0) * 68 + r] = v.x;
    rsT[(k4 + 1) * 68 + r] = v.y;
    rsT[(k4 + 2) * 68 + r] = v.z;
    rsT[(k4 + 3) * 68 + r] = v.w;
  }
  __syncthreads();
  int c0 = (tid & 15) * 4;
  int rr0 = (tid >> 4) * 4;
  float4 a0 = {0,0,0,0}, a1 = {0,0,0,0}, a2 = {0,0,0,0}, a3 = {0,0,0,0};
  #pragma unroll 4
  for (int k = 0; k < 64; ++k){
    float4 rv = *(const float4*)&rsT[k * 68 + rr0];
    float4 wv = *(const float4*)&Ws[k * 64 + c0];
    a0.x += rv.x*wv.x; a0.y += rv.x*wv.y; a0.z += rv.x*wv.z; a0.w += rv.x*wv.w;
    a1.x += rv.y*wv.x; a1.y += rv.y*wv.y; a1.z += rv.y*wv.z; a1.w += rv.y*wv.w;
    a2.x += rv.z*wv.x; a2.y += rv.z*wv.y; a2.z += rv.z*wv.z; a2.w += rv.z*wv.w;
    a3.x += rv.w*wv.x; a3.y += rv.w*wv.y; a3.z += rv.w*wv.z; a3.w += rv.w*wv.w;
  }
  store_bf4(&outp[(r0 + rr0 + 0) * 64 + c0], a0);
  store_bf4(&outp[(r0 + rr0 + 1) * 64 + c0], a1);
  store_bf4(&outp[(r0 + rr0 + 2) * 64 + c0], a2);
  store_bf4(&outp[(r0 + rr0 + 3) * 64 + c0], a3);
  // attention epilogue (fp32 registers)
  float4 as4 = *(const float4*)&att_s[c0];
  float4 ad4 = *(const float4*)&att_d[c0];
  float4 aq[4] = {a0, a1, a2, a3};
  float ps[4], pd[4];
  #pragma unroll
  for (int q = 0; q < 4; ++q){
    ps[q] = aq[q].x*as4.x + aq[q].y*as4.y + aq[q].z*as4.z + aq[q].w*as4.w;
    pd[q] = aq[q].x*ad4.x + aq[q].y*ad4.y + aq[q].z*ad4.z + aq[q].w*ad4.w;
  }
  #pragma unroll
  for (int q = 0; q < 4; ++q){
    ps[q] += __shfl_xor(ps[q], 1, 64); ps[q] += __shfl_xor(ps[q], 2, 64);
    pd[q] += __shfl_xor(pd[q], 1, 64); pd[q] += __shfl_xor(pd[q], 2, 64);
  }
  if ((tid & 3) == 0){
    int head = c0 >> 4;
    #pragma unroll
    for (int q = 0; q < 4; ++q){
      size_t row = r0 + rr0 + q;
      asrc[row * 4 + head] = ps[q];
      adst[row * 4 + head] = pd[q];
    }
  }
}

// GCN aggregate v5: block = (node n, group of 32 graphs); 8 graphs per wave.
__global__ __launch_bounds__(256) void k_gcn_agg(const bf* __restrict__ hw,
    const int2* __restrict__ epack, const int* __restrict__ offs,
    const float* __restrict__ b_gcn, float* __restrict__ gout){
  __shared__ int2 eS[ECAP];
  int nb = blockIdx.x;              // 0..1479
  int n = nb % N_;
  int gg = nb / N_;                 // 0..3
  int tid = threadIdx.x;
  int o0 = offs[n], o1 = offs[n + 1];
  int deg = o1 - o0;
  int cap = deg < ECAP ? deg : ECAP;
  for (int i = tid; i < cap; i += 256) eS[i] = epack[o0 + i];
  __syncthreads();
  int wv = tid >> 6, c = tid & 63;
  int g0 = gg * 32 + wv * 8;
  const bf* hb = hw + (size_t)g0 * NH_ + c;
  float a[8];
  #pragma unroll
  for (int q = 0; q < 8; ++q) a[q] = 0.f;
  int p = 0;
  for (; p + 2 <= cap; p += 2){
    int2 e0 = eS[p], e1 = eS[p+1];
    float w0 = __int_as_float(e0.y), w1 = __int_as_float(e1.y);
    float v0[8], v1[8];
    #pragma unroll
    for (int q = 0; q < 8; ++q){
      v0[q] = b2f(hb[(size_t)q * NH_ + e0.x]);
      v1[q] = b2f(hb[(size_t)q * NH_ + e1.x]);
    }
    #pragma unroll
    for (int q = 0; q < 8; ++q) a[q] += w0 * v0[q] + w1 * v1[q];
  }
  for (; p < cap; ++p){
    int2 e = eS[p];
    float w = __int_as_float(e.y);
    #pragma unroll
    for (int q = 0; q < 8; ++q) a[q] += w * b2f(hb[(size_t)q * NH_ + e.x]);
  }
  for (int r = cap; r < deg; ++r){      // overflow fallback (not expected)
    int2 e = epack[o0 + r];
    float w = __int_as_float(e.y);
    #pragma unroll
    for (int q = 0; q < 8; ++q) a[q] += w * b2f(hb[(size_t)q * NH_ + e.x]);
  }
  float bv = b_gcn[c];
  #pragma unroll
  for (int q = 0; q < 8; ++q)
    gout[((size_t)(g0 + q) * N_ + n) * 64 + c] = gelu_f(a[q] + bv);
}

// per (g,n,head): softmax max+denominator; writes UNNORMALIZED bf16 exp weights
__global__ void k_alpha(const float* __restrict__ asrc, const float* __restrict__ adst,
                        const int* __restrict__ csr_soff, const int* __restrict__ offs,
                        bf* __restrict__ alpha, float* __restrict__ invden){
  int idx = blockIdx.x * 256 + threadIdx.x;   // (g*N+n)*4+head, GN_*4 exact
  int head = idx & 3;
  int gn = idx >> 2;
  int g = gn / N_, n = gn - g * N_;
  int o0 = offs[n], o1 = offs[n + 1];
  const float* as_g = asrc + (size_t)g * (N_ * 4);
  float adv = adst[idx];
  float m = -1e30f;
  int p = o0;
  for (; p + 4 <= o1; p += 4){
    int sa = csr_soff[p+0] >> 4, sb = csr_soff[p+1] >> 4;
    int sc = csr_soff[p+2] >> 4, sd = csr_soff[p+3] >> 4;
    float va = lrelu(as_g[sa + head] + adv);
    float vb = lrelu(as_g[sb + head] + adv);
    float vc = lrelu(as_g[sc + head] + adv);
    float vd = lrelu(as_g[sd + head] + adv);
    m = fmaxf(m, fmaxf(fmaxf(va, vb), fmaxf(vc, vd)));
  }
  for (; p < o1; ++p)
    m = fmaxf(m, lrelu(as_g[(csr_soff[p] >> 4) + head] + adv));
  bf* al_g = alpha + (size_t)g * (E2_ * 4);
  float den = 0.f;
  p = o0;
  for (; p + 4 <= o1; p += 4){
    int sa = csr_soff[p+0] >> 4, sb = csr_soff[p+1] >> 4;
    int sc = csr_soff[p+2] >> 4, sd = csr_soff[p+3] >> 4;
    float ea = __expf(lrelu(as_g[sa + head] + adv) - m);
    float eb = __expf(lrelu(as_g[sb + head] + adv) - m);
    float ec = __expf(lrelu(as_g[sc + head] + adv) - m);
    float ed = __expf(lrelu(as_g[sd + head] + adv) - m);
    den += ea + eb + ec + ed;
    al_g[(p+0)*4 + head] = __float2bfloat16(ea);
    al_g[(p+1)*4 + head] = __float2bfloat16(eb);
    al_g[(p+2)*4 + head] = __float2bfloat16(ec);
    al_g[(p+3)*4 + head] = __float2bfloat16(ed);
  }
  for (; p < o1; ++p){
    float ex = __expf(lrelu(as_g[(csr_soff[p] >> 4) + head] + adv) - m);
    den += ex;
    al_g[p*4 + head] = __float2bfloat16(ex);
  }
  invden[idx] = 1.f / den;
}

// GAT aggregate v5: block = (node n, group of 32 graphs); 8 graphs/wave; bf16 gathers.
__global__ __launch_bounds__(256) void k_gat_agg(const bf* __restrict__ gh,
    const bf* __restrict__ alpha, const float* __restrict__ invden,
    const int* __restrict__ csr_soff, const int* __restrict__ offs,
    const float* __restrict__ b_gat, const float* __restrict__ ln_g,
    const float* __restrict__ ln_b, float* __restrict__ h){
  __shared__ int sS[ECAP];
  int nb = blockIdx.x;
  int n = nb % N_;
  int gg = nb / N_;                 // 0..3
  int tid = threadIdx.x;
  int o0 = offs[n], o1 = offs[n + 1];
  int deg = o1 - o0;
  int cap = deg < ECAP ? deg : ECAP;
  for (int i = tid; i < cap; i += 256) sS[i] = csr_soff[o0 + i];
  __syncthreads();
  int wv = tid >> 6, c = tid & 63;
  int g0 = gg * 32 + wv * 8;
  int head = c >> 4;
  const bf* gb = gh + (size_t)g0 * NH_ + c;
  const bf* ab = alpha + (size_t)g0 * (E2_ * 4) + (size_t)o0 * 4 + head;
  float a[8];
  #pragma unroll
  for (int q = 0; q < 8; ++q) a[q] = 0.f;
  int p = 0;
  for (; p + 2 <= cap; p += 2){
    int s0 = sS[p], s1 = sS[p+1];
    float x0[8], x1[8], v0[8], v1[8];
    #pragma unroll
    for (int q = 0; q < 8; ++q){
      const bf* aq = ab + (size_t)q * (E2_ * 4);
      x0[q] = b2f(aq[(p+0)*4]);
      x1[q] = b2f(aq[(p+1)*4]);
      v0[q] = b2f(gb[(size_t)q * NH_ + s0]);
      v1[q] = b2f(gb[(size_t)q * NH_ + s1]);
    }
    #pragma unroll
    for (int q = 0; q < 8; ++q) a[q] += x0[q] * v0[q] + x1[q] * v1[q];
  }
  for (; p < cap; ++p){
    int s = sS[p];
    #pragma unroll
    for (int q = 0; q < 8; ++q)
      a[q] += b2f(ab[(size_t)q * (E2_ * 4) + p*4]) * b2f(gb[(size_t)q * NH_ + s]);
  }
  for (int r = cap; r < deg; ++r){
    int s = csr_soff[o0 + r];
    #pragma unroll
    for (int q = 0; q < 8; ++q)
      a[q] += b2f(ab[(size_t)q * (E2_ * 4) + r*4]) * b2f(gb[(size_t)q * NH_ + s]);
  }
  float bgv = b_gat[c], lgv = ln_g[c], lbv = ln_b[c];
  #pragma unroll
  for (int q = 0; q < 8; ++q){
    int gn = (g0 + q) * N_ + n;
    float outv = a[q] * invden[(size_t)gn * 4 + head] + bgv;
    size_t hidx = (size_t)gn * 64 + c;
    float r = outv + h[hidx];
    float mu = wsum64(r) * (1.f / 64.f);
    float d = r - mu;
    float var = wsum64(d * d) * (1.f / 64.f);
    h[hidx] = d * rsqrtf(var + 1e-5f) * lgv + lbv;
  }
}

// Fused temporal: 1 bn per block, 4 waves = (ciH 0/1) x (tH 0/1);
// bf16 W loads; ci-split partials via LDS.
__global__ __launch_bounds__(256) void k_tfuse(const float* __restrict__ h,
    const bf* __restrict__ WT, const float* __restrict__ bt,
    float* __restrict__ z){
  __shared__ float tile[64 * 36];        // padded x tile
  __shared__ float red[2][64 * 17];      // ciH=1 partials, [tH][ho*17+r]
  int tid = threadIdx.x;
  int wv = tid >> 6, lane = tid & 63;
  int ciH = wv & 1, tH = wv >> 1;
  int t0 = tH * 16;
  int bn = blockIdx.x;
  int b = bn / N_, n = bn - b * N_;
  for (int i = tid; i < 2304; i += 256) tile[i] = 0.f;
  __syncthreads();
  for (int i = tid; i < 2048; i += 256){
    int t = i >> 6, ch = i & 63;
    tile[ch * 36 + 2 + t] = h[((size_t)(b * T_ + t) * N_ + n) * 64 + ch];
  }
  __syncthreads();
  int ho = lane;
  int ci0 = ciH * 32;
  for (int l = 0; l < 3; ++l){
    const bf* wl = WT + l * 20480 + ho;
    float bv = (ciH == 0) ? bt[l * 64 + ho] : 0.f;
    float acc[16];
    #pragma unroll
    for (int r = 0; r < 16; ++r) acc[r] = bv;
    for (int ci = ci0; ci < ci0 + 32; ci += 2){
      const bf* wpA = wl + ci * 320;
      const bf* wpB = wl + (ci + 1) * 320;
      float wA[5], wB[5];
      #pragma unroll
      for (int k = 0; k < 5; ++k){ wA[k] = b2f(wpA[k * 64]); wB[k] = b2f(wpB[k * 64]); }
      const float* xrA = &tile[ci * 36 + t0];
      const float* xrB = &tile[(ci + 1) * 36 + t0];
      float4 xa[5], xb[5];
      #pragma unroll
      for (int q = 0; q < 5; ++q){
        xa[q] = *(const float4*)&xrA[q * 4];
        xb[q] = *(const float4*)&xrB[q * 4];
      }
      float xwA[20], xwB[20];
      #pragma unroll
      for (int q = 0; q < 5; ++q){
        xwA[q*4+0] = xa[q].x; xwA[q*4+1] = xa[q].y; xwA[q*4+2] = xa[q].z; xwA[q*4+3] = xa[q].w;
        xwB[q*4+0] = xb[q].x; xwB[q*4+1] = xb[q].y; xwB[q*4+2] = xb[q].z; xwB[q*4+3] = xb[q].w;
      }
      #pragma unroll
      for (int k = 0; k < 5; ++k){
        #pragma unroll
        for (int r = 0; r < 16; ++r) acc[r] += xwA[r + k] * wA[k];
      }
      #pragma unroll
      for (int k = 0; k < 5; ++k){
        #pragma unroll
        for (int r = 0; r < 16; ++r) acc[r] += xwB[r + k] * wB[k];
      }
    }
    if (ciH == 1){
      #pragma unroll
      for (int r = 0; r < 16; ++r) red[tH][ho * 17 + r] = acc[r];
    }
    __syncthreads();
    if (ciH == 0){
      #pragma unroll
      for (int r = 0; r < 16; ++r){
        int ti = t0 + r;
        float v = acc[r] + red[tH][ho * 17 + r];
        tile[ho * 36 + 2 + ti] = gelu_f(v) + tile[ho * 36 + 2 + ti];
      }
    }
    __syncthreads();
  }
  for (int i = tid; i < 2048; i += 256){
    int t = i >> 6, ch = i & 63;
    z[(size_t)(b * T_ + t) * NH_ + n * 64 + ch] = tile[ch * 36 + 2 + t];
  }
}

// MLP layer 1 (split-K, NO atomics): grid (4 b-groups, 160 kchunks of 148)
__global__ __launch_bounds__(256) void k_mlp1(const float* __restrict__ z,
    const float* __restrict__ W1, float* __restrict__ pbuf){
  __shared__ float zs[KC_ * 36];    // [j][r], r=0..31, stride 36
  int b = blockIdx.x;               // 0..3
  int kc = blockIdx.y;              // 0..159
  int base = kc * KC_;
  int tid = threadIdx.x;
  for (int i = tid; i < KC_ * 32; i += 256){
    int r = i / KC_, j = i - r * KC_;
    zs[j * 36 + r] = z[(size_t)(b * T_ + r) * NH_ + base + j];
  }
  __syncthreads();
  int r0 = (tid >> 6) * 8;
  int c0 = (tid & 63) * 4;
  float4 acc[8];
  #pragma unroll
  for (int r = 0; r < 8; ++r) acc[r] = (float4){0,0,0,0};
  const float* wbase = W1 + (size_t)base * 256 + c0;
  #pragma unroll 2
  for (int j = 0; j < KC_; ++j){
    float4 wv = *(const float4*)&wbase[(size_t)j * 256];
    float4 za = *(const float4*)&zs[j * 36 + r0];
    float4 zb = *(const float4*)&zs[j * 36 + r0 + 4];
    float zv[8] = {za.x, za.y, za.z, za.w, zb.x, zb.y, zb.z, zb.w};
    #pragma unroll
    for (int q = 0; q < 8; ++q){
      acc[q].x += zv[q]*wv.x; acc[q].y += zv[q]*wv.y;
      acc[q].z += zv[q]*wv.z; acc[q].w += zv[q]*wv.w;
    }
  }
  float* pb = pbuf + (size_t)kc * 32768;
  #pragma unroll
  for (int rr = 0; rr < 8; ++rr){
    int row = b * T_ + r0 + rr;
    *(float4*)&pb[(size_t)row * 256 + c0] = acc[rr];
  }
}

// reduce partials: y1[i] = sum_kc pbuf[kc*32768 + i]
__global__ __launch_bounds__(256) void k_red(const float* __restrict__ pbuf,
                                             float* __restrict__ y1){
  int i = blockIdx.x * 256 + threadIdx.x;   // 32768 exact
  float s0 = 0.f, s1 = 0.f, s2 = 0.f, s3 = 0.f;
  const float* p = pbuf + i;
  #pragma unroll 2
  for (int k = 0; k < NKC_; k += 4){
    s0 += p[(size_t)(k+0) * 32768];
    s1 += p[(size_t)(k+1) * 32768];
    s2 += p[(size_t)(k+2) * 32768];
    s3 += p[(size_t)(k+3) * 32768];
  }
  y1[i] = (s0 + s1) + (s2 + s3);
}

// MLP layer 2: out[128,64] = gelu(y1+b1) @ W2 + b2
__global__ __launch_bounds__(64) void k_mlp2(const float* __restrict__ y1,
    const float* __restrict__ b1, const float* __restrict__ W2,
    const float* __restrict__ b2, float* __restrict__ outp){
  __shared__ float a[256];
  int row = blockIdx.x, tid = threadIdx.x;
  for (int i = tid; i < 256; i += 64) a[i] = gelu_f(y1[(size_t)row * 256 + i] + b1[i]);
  __syncthreads();
  float acc = b2[tid];
  for (int i = 0; i < 256; ++i) acc += a[i] * W2[i * 64 + tid];
  outp[row * 64 + tid] = acc;
}

extern "C" void kernel_launch(void* const* d_in, const int* in_sizes, int n_in,
                              void* d_out, int out_size, void* d_ws, size_t ws_size,
                              hipStream_t stream){
  const float* x     = (const float*)d_in[0];
  const int*   ei    = (const int*)  d_in[1];
  const float* ew    = (const float*)d_in[2];
  const float* W_gcn = (const float*)d_in[3];
  const float* b_gcn = (const float*)d_in[4];
  const float* W_gat = (const float*)d_in[5];
  const float* att_s = (const float*)d_in[6];
  const float* att_d = (const float*)d_in[7];
  const float* b_gat = (const float*)d_in[8];
  const float* W_t   = (const float*)d_in[9];
  const float* b_t   = (const float*)d_in[10];
  const float* ln_g  = (const float*)d_in[11];
  const float* ln_b  = (const float*)d_in[12];
  const float* W1    = (const float*)d_in[13];
  const float* b1    = (const float*)d_in[14];
  const float* W2    = (const float*)d_in[15];
  const float* b2    = (const float*)d_in[16];
  float* outp = (float*)d_out;

  float* F = (float*)d_ws;
  size_t off = 0;
  float* deg    = F + off; off += 512;
  float* gnorm  = F + off; off += 12288;
  float* csr_g  = F + off; off += 12288;
  float* asrc   = F + off; off += 189440;
  float* adst   = F + off; off += 189440;
  float* invden = F + off; off += 189440;
  float* y1     = F + off; off += 32768;
  float* WTf    = F + off; off += 61440;     // bf16 transposed temporal weights (slot in floats)
  float* h      = F + off; off += 3031040;
  float* bufB   = F + off; off += 3031040;   // hw (bf16, slot in floats)
  float* bufC   = F + off; off += 3031040;   // g (fp32)
  float* bufD   = F + off; off += 3031040;   // gh (bf16) / z (fp32)
  float* alphaf = F + off; off += (size_t)G_ * E2_ * 4;   // alpha (bf16) / pbuf (fp32)
  float* pbuf   = alphaf;                    // mlp1 partials: 160*32768 floats <= slot
  int* I        = (int*)(F + off);
  int* counts   = I;
  int* offs     = I + 512;
  int* cursor   = I + 1024;
  int* csr_soff = I + 1536;                  // E2_ entries (12288 slot)
  int2* epack   = (int2*)(I + 13824);        // E2_ int2 entries

  bf* WT     = (bf*)WTf;
  bf* hw16   = (bf*)bufB;
  bf* gh16   = (bf*)bufD;
  bf* alpha16= (bf*)alphaf;

  hipMemsetAsync(deg, 0, 512 * sizeof(float), stream);
  hipMemsetAsync(counts, 0, 512 * sizeof(int), stream);

  k_deg_count<<<48, 256, 0, stream>>>(ei, ew, deg, counts);
  k_gnorm<<<48, 256, 0, stream>>>(ei, ew, deg, gnorm);
  k_scan<<<1, 64, 0, stream>>>(counts, offs, cursor);
  k_fill<<<48, 256, 0, stream>>>(ei, gnorm, cursor, csr_soff, csr_g, epack);
  k_wtr<<<240, 256, 0, stream>>>(W_t, WT);
  hipMemcpyAsync(h, x, (size_t)GN_ * 64 * sizeof(float), hipMemcpyDeviceToDevice, stream);

  for (int l = 0; l < 3; ++l){
    k_rowgemm<<<740, 256, 0, stream>>>(h, W_gcn + l * 4096, hw16);
    k_gcn_agg<<<1480, 256, 0, stream>>>(hw16, epack, offs, b_gcn + l * 64, bufC);
    k_rowgemm_attn<<<740, 256, 0, stream>>>(bufC, W_gat + l * 4096, gh16,
                                            att_s + l * 64, att_d + l * 64, asrc, adst);
    k_alpha<<<740, 256, 0, stream>>>(asrc, adst, csr_soff, offs, alpha16, invden);
    k_gat_agg<<<1480, 256, 0, stream>>>(gh16, alpha16, invden, csr_soff, offs,
                                        b_gat + l * 64, ln_g + l * 64, ln_b + l * 64, h);
  }

  k_tfuse<<<BN_, 256, 0, stream>>>(h, WT, b_t, bufD);

  dim3 g1(4, NKC_);
  k_mlp1<<<g1, 256, 0, stream>>>(bufD, W1, pbuf);
  k_red<<<128, 256, 0, stream>>>(pbuf, y1);
  k_mlp2<<<128, 64, 0, stream>>>(y1, b1, W2, b2, outp);
}

// Round 17
// 526.014 us; speedup vs baseline: 1.2736x; 1.1114x over previous
//
#include <hip/hip_runtime.h>
#include <hip/hip_bf16.h>

// Problem constants
#define B_   4
#define T_   32
#define N_   370
#define E_   11840
#define E2_  12210          // E_ + N_ self loops
#define H_   64
#define G_   128            // B_*T_
#define GN_  47360          // G_*N_
#define BN_  1480           // B_*N_
#define NH_  23680          // N_*H_
#define ECAP 320            // LDS edge-stage capacity per node (max deg ~70)
#define KC_  148            // mlp1 k-chunk (23680 = 148*160)
#define NKC_ 160            // number of k-chunks

typedef __hip_bfloat16 bf;

__device__ __forceinline__ float gelu_f(float x){
  return 0.5f * x * (1.0f + erff(x * 0.7071067811865475f));
}
__device__ __forceinline__ float lrelu(float v){ return v > 0.f ? v : 0.2f * v; }
__device__ __forceinline__ float b2f(bf x){ return __bfloat162float(x); }
__device__ __forceinline__ void store_bf4(bf* p, float4 v){
  bf tmp[4] = {__float2bfloat16(v.x), __float2bfloat16(v.y),
               __float2bfloat16(v.z), __float2bfloat16(v.w)};
  *(ushort4*)p = *(const ushort4*)tmp;
}
// load 8 consecutive bf16 (16B aligned) -> 8 floats
__device__ __forceinline__ void load_bf8(const bf* p, float* v){
  uint4 u = *(const uint4*)p;
  unsigned ua[4] = {u.x, u.y, u.z, u.w};
  #pragma unroll
  for (int i = 0; i < 4; ++i){
    v[2*i]   = __uint_as_float(ua[i] << 16);
    v[2*i+1] = __uint_as_float(ua[i] & 0xffff0000u);
  }
}

// ---------- edge preprocessing ----------
__global__ void k_deg_count(const int* __restrict__ ei, const float* __restrict__ ew,
                            float* __restrict__ deg, int* __restrict__ counts){
  int e = blockIdx.x * 256 + threadIdx.x;
  if (e >= E2_) return;
  int dst = (e < E_) ? ei[E_ + e] : (e - E_);
  float w = (e < E_) ? ew[e] : 1.0f;
  atomicAdd(&deg[dst], w);
  atomicAdd(&counts[dst], 1);
}

__global__ void k_gnorm(const int* __restrict__ ei, const float* __restrict__ ew,
                        const float* __restrict__ deg, float* __restrict__ gnorm){
  int e = blockIdx.x * 256 + threadIdx.x;
  if (e >= E2_) return;
  int s = (e < E_) ? ei[e] : (e - E_);
  int d = (e < E_) ? ei[E_ + e] : (e - E_);
  float w = (e < E_) ? ew[e] : 1.0f;
  float ds = deg[s] > 0.f ? rsqrtf(deg[s]) : 0.f;
  float dd = deg[d] > 0.f ? rsqrtf(deg[d]) : 0.f;
  gnorm[e] = ds * w * dd;
}

// wave-parallel exclusive scan over counts (one wave)
__global__ void k_scan(const int* __restrict__ counts, int* __restrict__ offs,
                       int* __restrict__ cursor){
  int lane = threadIdx.x;
  int run = 0;
  for (int c0 = 0; c0 < N_; c0 += 64){
    int n = c0 + lane;
    int v = (n < N_) ? counts[n] : 0;
    int s = v;
    #pragma unroll
    for (int m = 1; m < 64; m <<= 1){
      int t = __shfl_up(s, m, 64);
      if (lane >= m) s += t;
    }
    int excl = run + s - v;
    if (n < N_){ offs[n] = excl; cursor[n] = excl; }
    run += __shfl(s, 63, 64);
  }
  if (lane == 0) offs[N_] = run;
}

// stores s*8192 (= s*G*64, row offset in [n][g][c] bf16 layout) + gnorm
__global__ void k_fill(const int* __restrict__ ei, const float* __restrict__ gnorm,
                       int* __restrict__ cursor, int* __restrict__ csr_soff,
                       float* __restrict__ csr_g, int2* __restrict__ epack){
  int e = blockIdx.x * 256 + threadIdx.x;
  if (e >= E2_) return;
  int s = (e < E_) ? ei[e] : (e - E_);
  int d = (e < E_) ? ei[E_ + e] : (e - E_);
  int pos = atomicAdd(&cursor[d], 1);
  csr_soff[pos] = s << 13;            // s*8192
  float gw = gnorm[e];
  csr_g[pos] = gw;
  epack[pos] = make_int2(s << 13, __float_as_int(gw));
}

// transpose temporal-conv weights to bf16: WT[l][(ci*5+k)*64+ho]
__global__ void k_wtr(const float* __restrict__ Wt, bf* __restrict__ WT){
  int i = blockIdx.x * 256 + threadIdx.x;     // 3*20480 exact
  int l = i / 20480, rem = i - l * 20480;
  int ho = rem / 320, j = rem - ho * 320;
  WT[l * 20480 + j * 64 + ho] = __float2bfloat16(Wt[i]);
}

// rows x 64 @ 64 x 64 -> bf16 out with row remap g*N+n -> n*G+g (GCN transform)
__global__ __launch_bounds__(256) void k_rowgemm_t(const float* __restrict__ in,
                                                   const float* __restrict__ W,
                                                   bf* __restrict__ outp){
  __shared__ float Ws[64 * 64];
  __shared__ float rsT[64 * 68];
  int tid = threadIdx.x;
  size_t r0 = (size_t)blockIdx.x * 64;
  #pragma unroll
  for (int i = tid; i < 1024; i += 256)
    *(float4*)&Ws[i * 4] = *(const float4*)&W[i * 4];
  #pragma unroll
  for (int i = tid; i < 1024; i += 256){
    int r = i >> 4, k4 = (i & 15) * 4;
    float4 v = *(const float4*)&in[(r0 + r) * 64 + k4];
    rsT[(k4 + 0) * 68 + r] = v.x;
    rsT[(k4 + 1) * 68 + r] = v.y;
    rsT[(k4 + 2) * 68 + r] = v.z;
    rsT[(k4 + 3) * 68 + r] = v.w;
  }
  __syncthreads();
  int c0 = (tid & 15) * 4;
  int rr0 = (tid >> 4) * 4;
  float4 a0 = {0,0,0,0}, a1 = {0,0,0,0}, a2 = {0,0,0,0}, a3 = {0,0,0,0};
  #pragma unroll 4
  for (int k = 0; k < 64; ++k){
    float4 rv = *(const float4*)&rsT[k * 68 + rr0];
    float4 wv = *(const float4*)&Ws[k * 64 + c0];
    a0.x += rv.x*wv.x; a0.y += rv.x*wv.y; a0.z += rv.x*wv.z; a0.w += rv.x*wv.w;
    a1.x += rv.y*wv.x; a1.y += rv.y*wv.y; a1.z += rv.y*wv.z; a1.w += rv.y*wv.w;
    a2.x += rv.z*wv.x; a2.y += rv.z*wv.y; a2.z += rv.z*wv.z; a2.w += rv.z*wv.w;
    a3.x += rv.w*wv.x; a3.y += rv.w*wv.y; a3.z += rv.w*wv.z; a3.w += rv.w*wv.w;
  }
  float4 acc[4] = {a0, a1, a2, a3};
  #pragma unroll
  for (int q = 0; q < 4; ++q){
    int r = (int)(r0 + rr0 + q);          // = g*N + n
    int g = r / N_, n = r - g * N_;
    store_bf4(&outp[((size_t)n * G_ + g) * 64 + c0], acc[q]);
  }
}

// rowgemm + fused attention scores (rows stay n*G+g); bf16 output
__global__ __launch_bounds__(256) void k_rowgemm_attn(const float* __restrict__ in,
    const float* __restrict__ W, bf* __restrict__ outp,
    const float* __restrict__ att_s, const float* __restrict__ att_d,
    float* __restrict__ asrc, float* __restrict__ adst){
  __shared__ float Ws[64 * 64];
  __shared__ float rsT[64 * 68];
  int tid = threadIdx.x;
  size_t r0 = (size_t)blockIdx.x * 64;
  #pragma unroll
  for (int i = tid; i < 1024; i += 256)
    *(float4*)&Ws[i * 4] = *(const float4*)&W[i * 4];
  #pragma unroll
  for (int i = tid; i < 1024; i += 256){
    int r = i >> 4, k4 = (i & 15) * 4;
    float4 v = *(const float4*)&in[(r0 + r) * 64 + k4];
    rsT[(k4 + 0) * 68 + r] = v.x;
    rsT[(k4 + 1) * 68 + r] = v.y;
    rsT[(k4 + 2) * 68 + r] = v.z;
    rsT[(k4 + 3) * 68 + r] = v.w;
  }
  __syncthreads();
  int c0 = (tid & 15) * 4;
  int rr0 = (tid >> 4) * 4;
  float4 a0 = {0,0,0,0}, a1 = {0,0,0,0}, a2 = {0,0,0,0}, a3 = {0,0,0,0};
  #pragma unroll 4
  for (int k = 0; k < 64; ++k){
    float4 rv = *(const float4*)&rsT[k * 68 + rr0];
    float4 wv = *(const float4*)&Ws[k * 64 + c0];
    a0.x += rv.x*wv.x; a0.y += rv.x*wv.y; a0.z += rv.x*wv.z; a0.w += rv.x*wv.w;
    a1.x += rv.y*wv.x; a1.y += rv.y*wv.y; a1.z += rv.y*wv.z; a1.w += rv.y*wv.w;
    a2.x += rv.z*wv.x; a2.y += rv.z*wv.y; a2.z += rv.z*wv.z; a2.w += rv.z*wv.w;
    a3.x += rv.w*wv.x; a3.y += rv.w*wv.y; a3.z += rv.w*wv.z; a3.w += rv.w*wv.w;
  }
  store_bf4(&outp[(r0 + rr0 + 0) * 64 + c0], a0);
  store_bf4(&outp[(r0 + rr0 + 1) * 64 + c0], a1);
  store_bf4(&outp[(r0 + rr0 + 2) * 64 + c0], a2);
  store_bf4(&outp[(r0 + rr0 + 3) * 64 + c0], a3);
  float4 as4 = *(const float4*)&att_s[c0];
  float4 ad4 = *(const float4*)&att_d[c0];
  float4 aq[4] = {a0, a1, a2, a3};
  float ps[4], pd[4];
  #pragma unroll
  for (int q = 0; q < 4; ++q){
    ps[q] = aq[q].x*as4.x + aq[q].y*as4.y + aq[q].z*as4.z + aq[q].w*as4.w;
    pd[q] = aq[q].x*ad4.x + aq[q].y*ad4.y + aq[q].z*ad4.z + aq[q].w*ad4.w;
  }
  #pragma unroll
  for (int q = 0; q < 4; ++q){
    ps[q] += __shfl_xor(ps[q], 1, 64); ps[q] += __shfl_xor(ps[q], 2, 64);
    pd[q] += __shfl_xor(pd[q], 1, 64); pd[q] += __shfl_xor(pd[q], 2, 64);
  }
  if ((tid & 3) == 0){
    int head = c0 >> 4;
    #pragma unroll
    for (int q = 0; q < 4; ++q){
      size_t row = r0 + rr0 + q;
      asrc[row * 4 + head] = ps[q];
      adst[row * 4 + head] = pd[q];
    }
  }
}

// GCN aggregate v6: block = (node n, group of 32 graphs); thread = (graph, c-octet).
// Per edge: ONE coalesced 16B load per thread from [n][g][c] bf16 layout.
__global__ __launch_bounds__(256) void k_gcn_agg(const bf* __restrict__ hw,
    const int2* __restrict__ epack, const int* __restrict__ offs,
    const float* __restrict__ b_gcn, float* __restrict__ gout){
  __shared__ int2 eS[ECAP];
  int nb = blockIdx.x;              // 0..1479
  int n = nb % N_;
  int gg = nb / N_;                 // 0..3
  int tid = threadIdx.x;
  int o0 = offs[n], o1 = offs[n + 1];
  int deg = o1 - o0;
  int cap = deg < ECAP ? deg : ECAP;
  for (int i = tid; i < cap; i += 256) eS[i] = epack[o0 + i];
  __syncthreads();
  int ql = tid >> 3, c8 = tid & 7;
  int g = gg * 32 + ql;
  int toff = gg * 2048 + ql * 64 + c8 * 8;
  float a[8];
  #pragma unroll
  for (int j = 0; j < 8; ++j) a[j] = 0.f;
  int p = 0;
  for (; p + 2 <= cap; p += 2){
    int2 e0 = eS[p], e1 = eS[p+1];
    float w0 = __int_as_float(e0.y), w1 = __int_as_float(e1.y);
    float v0[8], v1[8];
    load_bf8(hw + e0.x + toff, v0);
    load_bf8(hw + e1.x + toff, v1);
    #pragma unroll
    for (int j = 0; j < 8; ++j) a[j] += w0 * v0[j] + w1 * v1[j];
  }
  for (; p < cap; ++p){
    int2 e = eS[p];
    float w = __int_as_float(e.y);
    float v[8];
    load_bf8(hw + e.x + toff, v);
    #pragma unroll
    for (int j = 0; j < 8; ++j) a[j] += w * v[j];
  }
  for (int r = cap; r < deg; ++r){      // overflow fallback (not expected)
    int2 e = epack[o0 + r];
    float w = __int_as_float(e.y);
    float v[8];
    load_bf8(hw + e.x + toff, v);
    #pragma unroll
    for (int j = 0; j < 8; ++j) a[j] += w * v[j];
  }
  float4 b0 = *(const float4*)&b_gcn[c8 * 8];
  float4 b1 = *(const float4*)&b_gcn[c8 * 8 + 4];
  float bb[8] = {b0.x, b0.y, b0.z, b0.w, b1.x, b1.y, b1.z, b1.w};
  float* op = &gout[((size_t)n * G_ + g) * 64 + c8 * 8];
  float4 o0v, o1v;
  o0v.x = gelu_f(a[0]+bb[0]); o0v.y = gelu_f(a[1]+bb[1]);
  o0v.z = gelu_f(a[2]+bb[2]); o0v.w = gelu_f(a[3]+bb[3]);
  o1v.x = gelu_f(a[4]+bb[4]); o1v.y = gelu_f(a[5]+bb[5]);
  o1v.z = gelu_f(a[6]+bb[6]); o1v.w = gelu_f(a[7]+bb[7]);
  *(float4*)&op[0] = o0v;
  *(float4*)&op[4] = o1v;
}

// per (row=n*G+g, head): softmax over incoming edges; alpha layout [p][head][g] bf16
__global__ void k_alpha(const float* __restrict__ asrc, const float* __restrict__ adst,
                        const int* __restrict__ csr_soff, const int* __restrict__ offs,
                        bf* __restrict__ alpha, float* __restrict__ invden){
  int idx = blockIdx.x * 256 + threadIdx.x;   // row*4+head, GN_*4 exact
  int head = idx & 3;
  int row = idx >> 2;
  int g = row & 127;
  int n = row >> 7;
  int o0 = offs[n], o1 = offs[n + 1];
  int gh4 = (g << 2) + head;
  float adv = adst[idx];
  float m = -1e30f;
  int p = o0;
  for (; p + 4 <= o1; p += 4){
    int sa = csr_soff[p+0] >> 4, sb = csr_soff[p+1] >> 4;   // s*512
    int sc = csr_soff[p+2] >> 4, sd = csr_soff[p+3] >> 4;
    float va = lrelu(asrc[sa + gh4] + adv);
    float vb = lrelu(asrc[sb + gh4] + adv);
    float vc = lrelu(asrc[sc + gh4] + adv);
    float vd = lrelu(asrc[sd + gh4] + adv);
    m = fmaxf(m, fmaxf(fmaxf(va, vb), fmaxf(vc, vd)));
  }
  for (; p < o1; ++p)
    m = fmaxf(m, lrelu(asrc[(csr_soff[p] >> 4) + gh4] + adv));
  float den = 0.f;
  int hg = (head << 7) + g;
  p = o0;
  for (; p + 4 <= o1; p += 4){
    int sa = csr_soff[p+0] >> 4, sb = csr_soff[p+1] >> 4;
    int sc = csr_soff[p+2] >> 4, sd = csr_soff[p+3] >> 4;
    float ea = __expf(lrelu(asrc[sa + gh4] + adv) - m);
    float eb = __expf(lrelu(asrc[sb + gh4] + adv) - m);
    float ec = __expf(lrelu(asrc[sc + gh4] + adv) - m);
    float ed = __expf(lrelu(asrc[sd + gh4] + adv) - m);
    den += ea + eb + ec + ed;
    alpha[(size_t)(p+0) * 512 + hg] = __float2bfloat16(ea);
    alpha[(size_t)(p+1) * 512 + hg] = __float2bfloat16(eb);
    alpha[(size_t)(p+2) * 512 + hg] = __float2bfloat16(ec);
    alpha[(size_t)(p+3) * 512 + hg] = __float2bfloat16(ed);
  }
  for (; p < o1; ++p){
    float ex = __expf(lrelu(asrc[(csr_soff[p] >> 4) + gh4] + adv) - m);
    den += ex;
    alpha[(size_t)p * 512 + hg] = __float2bfloat16(ex);
  }
  invden[idx] = 1.f / den;
}

// GAT aggregate v6: block = (node n, 32 graphs); thread = (graph, c-octet).
// Per edge: 1 coalesced 16B feature load + 1 alpha bf16 load per thread.
// Epilogue: bias + residual + LayerNorm (8-lane shuffle reduce), h in [g][n][c].
__global__ __launch_bounds__(256) void k_gat_agg(const bf* __restrict__ gh,
    const bf* __restrict__ alpha, const float* __restrict__ invden,
    const int* __restrict__ csr_soff, const int* __restrict__ offs,
    const float* __restrict__ b_gat, const float* __restrict__ ln_g,
    const float* __restrict__ ln_b, float* __restrict__ h){
  __shared__ int sS[ECAP];
  int nb = blockIdx.x;
  int n = nb % N_;
  int gg = nb / N_;
  int tid = threadIdx.x;
  int o0 = offs[n], o1 = offs[n + 1];
  int deg = o1 - o0;
  int cap = deg < ECAP ? deg : ECAP;
  for (int i = tid; i < cap; i += 256) sS[i] = csr_soff[o0 + i];
  __syncthreads();
  int ql = tid >> 3, c8 = tid & 7;
  int g = gg * 32 + ql;
  int head = c8 >> 1;
  int toff = gg * 2048 + ql * 64 + c8 * 8;
  const bf* ap = alpha + (size_t)o0 * 512 + (head << 7) + g;
  float a[8];
  #pragma unroll
  for (int j = 0; j < 8; ++j) a[j] = 0.f;
  int p = 0;
  for (; p + 2 <= cap; p += 2){
    int s0 = sS[p], s1 = sS[p+1];
    float x0 = b2f(ap[(size_t)(p+0) * 512]);
    float x1 = b2f(ap[(size_t)(p+1) * 512]);
    float v0[8], v1[8];
    load_bf8(gh + s0 + toff, v0);
    load_bf8(gh + s1 + toff, v1);
    #pragma unroll
    for (int j = 0; j < 8; ++j) a[j] += x0 * v0[j] + x1 * v1[j];
  }
  for (; p < cap; ++p){
    float x = b2f(ap[(size_t)p * 512]);
    float v[8];
    load_bf8(gh + sS[p] + toff, v);
    #pragma unroll
    for (int j = 0; j < 8; ++j) a[j] += x * v[j];
  }
  for (int r = cap; r < deg; ++r){
    float x = b2f(ap[(size_t)r * 512]);
    float v[8];
    load_bf8(gh + csr_soff[o0 + r] + toff, v);
    #pragma unroll
    for (int j = 0; j < 8; ++j) a[j] += x * v[j];
  }
  float inv = invden[(((size_t)n << 7) + g) * 4 + head];
  float4 bg0 = *(const float4*)&b_gat[c8 * 8];
  float4 bg1 = *(const float4*)&b_gat[c8 * 8 + 4];
  float bb[8] = {bg0.x, bg0.y, bg0.z, bg0.w, bg1.x, bg1.y, bg1.z, bg1.w};
  size_t hbase = ((size_t)g * N_ + n) * 64 + c8 * 8;
  float4 h0 = *(const float4*)&h[hbase];
  float4 h1 = *(const float4*)&h[hbase + 4];
  float hh[8] = {h0.x, h0.y, h0.z, h0.w, h1.x, h1.y, h1.z, h1.w};
  float r8[8];
  float s1 = 0.f;
  #pragma unroll
  for (int j = 0; j < 8; ++j){
    r8[j] = a[j] * inv + bb[j] + hh[j];
    s1 += r8[j];
  }
  s1 += __shfl_xor(s1, 1, 64); s1 += __shfl_xor(s1, 2, 64); s1 += __shfl_xor(s1, 4, 64);
  float mu = s1 * (1.f / 64.f);
  float s2 = 0.f;
  #pragma unroll
  for (int j = 0; j < 8; ++j){
    float d = r8[j] - mu;
    s2 += d * d;
  }
  s2 += __shfl_xor(s2, 1, 64); s2 += __shfl_xor(s2, 2, 64); s2 += __shfl_xor(s2, 4, 64);
  float rstd = rsqrtf(s2 * (1.f / 64.f) + 1e-5f);
  float4 lg0 = *(const float4*)&ln_g[c8 * 8];
  float4 lg1 = *(const float4*)&ln_g[c8 * 8 + 4];
  float4 lb0 = *(const float4*)&ln_b[c8 * 8];
  float4 lb1 = *(const float4*)&ln_b[c8 * 8 + 4];
  float lg[8] = {lg0.x, lg0.y, lg0.z, lg0.w, lg1.x, lg1.y, lg1.z, lg1.w};
  float lb[8] = {lb0.x, lb0.y, lb0.z, lb0.w, lb1.x, lb1.y, lb1.z, lb1.w};
  float4 w0, w1;
  w0.x = (r8[0]-mu)*rstd*lg[0]+lb[0]; w0.y = (r8[1]-mu)*rstd*lg[1]+lb[1];
  w0.z = (r8[2]-mu)*rstd*lg[2]+lb[2]; w0.w = (r8[3]-mu)*rstd*lg[3]+lb[3];
  w1.x = (r8[4]-mu)*rstd*lg[4]+lb[4]; w1.y = (r8[5]-mu)*rstd*lg[5]+lb[5];
  w1.z = (r8[6]-mu)*rstd*lg[6]+lb[6]; w1.w = (r8[7]-mu)*rstd*lg[7]+lb[7];
  *(float4*)&h[hbase] = w0;
  *(float4*)&h[hbase + 4] = w1;
}

// Fused temporal: 1 bn per block, 4 waves = (ciH 0/1) x (tH 0/1);
// bf16 W loads; ci-split partials via LDS.
__global__ __launch_bounds__(256) void k_tfuse(const float* __restrict__ h,
    const bf* __restrict__ WT, const float* __restrict__ bt,
    float* __restrict__ z){
  __shared__ float tile[64 * 36];        // padded x tile
  __shared__ float red[2][64 * 17];      // ciH=1 partials, [tH][ho*17+r]
  int tid = threadIdx.x;
  int wv = tid >> 6, lane = tid & 63;
  int ciH = wv & 1, tH = wv >> 1;
  int t0 = tH * 16;
  int bn = blockIdx.x;
  int b = bn / N_, n = bn - b * N_;
  for (int i = tid; i < 2304; i += 256) tile[i] = 0.f;
  __syncthreads();
  for (int i = tid; i < 2048; i += 256){
    int t = i >> 6, ch = i & 63;
    tile[ch * 36 + 2 + t] = h[((size_t)(b * T_ + t) * N_ + n) * 64 + ch];
  }
  __syncthreads();
  int ho = lane;
  int ci0 = ciH * 32;
  for (int l = 0; l < 3; ++l){
    const bf* wl = WT + l * 20480 + ho;
    float bv = (ciH == 0) ? bt[l * 64 + ho] : 0.f;
    float acc[16];
    #pragma unroll
    for (int r = 0; r < 16; ++r) acc[r] = bv;
    for (int ci = ci0; ci < ci0 + 32; ci += 2){
      const bf* wpA = wl + ci * 320;
      const bf* wpB = wl + (ci + 1) * 320;
      float wA[5], wB[5];
      #pragma unroll
      for (int k = 0; k < 5; ++k){ wA[k] = b2f(wpA[k * 64]); wB[k] = b2f(wpB[k * 64]); }
      const float* xrA = &tile[ci * 36 + t0];
      const float* xrB = &tile[(ci + 1) * 36 + t0];
      float4 xa[5], xb[5];
      #pragma unroll
      for (int q = 0; q < 5; ++q){
        xa[q] = *(const float4*)&xrA[q * 4];
        xb[q] = *(const float4*)&xrB[q * 4];
      }
      float xwA[20], xwB[20];
      #pragma unroll
      for (int q = 0; q < 5; ++q){
        xwA[q*4+0] = xa[q].x; xwA[q*4+1] = xa[q].y; xwA[q*4+2] = xa[q].z; xwA[q*4+3] = xa[q].w;
        xwB[q*4+0] = xb[q].x; xwB[q*4+1] = xb[q].y; xwB[q*4+2] = xb[q].z; xwB[q*4+3] = xb[q].w;
      }
      #pragma unroll
      for (int k = 0; k < 5; ++k){
        #pragma unroll
        for (int r = 0; r < 16; ++r) acc[r] += xwA[r + k] * wA[k];
      }
      #pragma unroll
      for (int k = 0; k < 5; ++k){
        #pragma unroll
        for (int r = 0; r < 16; ++r) acc[r] += xwB[r + k] * wB[k];
      }
    }
    if (ciH == 1){
      #pragma unroll
      for (int r = 0; r < 16; ++r) red[tH][ho * 17 + r] = acc[r];
    }
    __syncthreads();
    if (ciH == 0){
      #pragma unroll
      for (int r = 0; r < 16; ++r){
        int ti = t0 + r;
        float v = acc[r] + red[tH][ho * 17 + r];
        tile[ho * 36 + 2 + ti] = gelu_f(v) + tile[ho * 36 + 2 + ti];
      }
    }
    __syncthreads();
  }
  for (int i = tid; i < 2048; i += 256){
    int t = i >> 6, ch = i & 63;
    z[(size_t)(b * T_ + t) * NH_ + n * 64 + ch] = tile[ch * 36 + 2 + t];
  }
}

// MLP layer 1 (split-K, NO atomics): grid (4 b-groups, 160 kchunks of 148)
__global__ __launch_bounds__(256) void k_mlp1(const float* __restrict__ z,
    const float* __restrict__ W1, float* __restrict__ pbuf){
  __shared__ float zs[KC_ * 36];    // [j][r], r=0..31, stride 36
  int b = blockIdx.x;               // 0..3
  int kc = blockIdx.y;              // 0..159
  int base = kc * KC_;
  int tid = threadIdx.x;
  for (int i = tid; i < KC_ * 32; i += 256){
    int r = i / KC_, j = i - r * KC_;
    zs[j * 36 + r] = z[(size_t)(b * T_ + r) * NH_ + base + j];
  }
  __syncthreads();
  int r0 = (tid >> 6) * 8;
  int c0 = (tid & 63) * 4;
  float4 acc[8];
  #pragma unroll
  for (int r = 0; r < 8; ++r) acc[r] = (float4){0,0,0,0};
  const float* wbase = W1 + (size_t)base * 256 + c0;
  #pragma unroll 2
  for (int j = 0; j < KC_; ++j){
    float4 wv = *(const float4*)&wbase[(size_t)j * 256];
    float4 za = *(const float4*)&zs[j * 36 + r0];
    float4 zb = *(const float4*)&zs[j * 36 + r0 + 4];
    float zv[8] = {za.x, za.y, za.z, za.w, zb.x, zb.y, zb.z, zb.w};
    #pragma unroll
    for (int q = 0; q < 8; ++q){
      acc[q].x += zv[q]*wv.x; acc[q].y += zv[q]*wv.y;
      acc[q].z += zv[q]*wv.z; acc[q].w += zv[q]*wv.w;
    }
  }
  float* pb = pbuf + (size_t)kc * 32768;
  #pragma unroll
  for (int rr = 0; rr < 8; ++rr){
    int row = b * T_ + r0 + rr;
    *(float4*)&pb[(size_t)row * 256 + c0] = acc[rr];
  }
}

// reduce partials: y1[i] = sum_kc pbuf[kc*32768 + i]
__global__ __launch_bounds__(256) void k_red(const float* __restrict__ pbuf,
                                             float* __restrict__ y1){
  int i = blockIdx.x * 256 + threadIdx.x;   // 32768 exact
  float s0 = 0.f, s1 = 0.f, s2 = 0.f, s3 = 0.f;
  const float* p = pbuf + i;
  #pragma unroll 2
  for (int k = 0; k < NKC_; k += 4){
    s0 += p[(size_t)(k+0) * 32768];
    s1 += p[(size_t)(k+1) * 32768];
    s2 += p[(size_t)(k+2) * 32768];
    s3 += p[(size_t)(k+3) * 32768];
  }
  y1[i] = (s0 + s1) + (s2 + s3);
}

// MLP layer 2: out[128,64] = gelu(y1+b1) @ W2 + b2
__global__ __launch_bounds__(64) void k_mlp2(const float* __restrict__ y1,
    const float* __restrict__ b1, const float* __restrict__ W2,
    const float* __restrict__ b2, float* __restrict__ outp){
  __shared__ float a[256];
  int row = blockIdx.x, tid = threadIdx.x;
  for (int i = tid; i < 256; i += 64) a[i] = gelu_f(y1[(size_t)row * 256 + i] + b1[i]);
  __syncthreads();
  float acc = b2[tid];
  for (int i = 0; i < 256; ++i) acc += a[i] * W2[i * 64 + tid];
  outp[row * 64 + tid] = acc;
}

extern "C" void kernel_launch(void* const* d_in, const int* in_sizes, int n_in,
                              void* d_out, int out_size, void* d_ws, size_t ws_size,
                              hipStream_t stream){
  const float* x     = (const float*)d_in[0];
  const int*   ei    = (const int*)  d_in[1];
  const float* ew    = (const float*)d_in[2];
  const float* W_gcn = (const float*)d_in[3];
  const float* b_gcn = (const float*)d_in[4];
  const float* W_gat = (const float*)d_in[5];
  const float* att_s = (const float*)d_in[6];
  const float* att_d = (const float*)d_in[7];
  const float* b_gat = (const float*)d_in[8];
  const float* W_t   = (const float*)d_in[9];
  const float* b_t   = (const float*)d_in[10];
  const float* ln_g  = (const float*)d_in[11];
  const float* ln_b  = (const float*)d_in[12];
  const float* W1    = (const float*)d_in[13];
  const float* b1    = (const float*)d_in[14];
  const float* W2    = (const float*)d_in[15];
  const float* b2    = (const float*)d_in[16];
  float* outp = (float*)d_out;

  float* F = (float*)d_ws;
  size_t off = 0;
  float* deg    = F + off; off += 512;
  float* gnorm  = F + off; off += 12288;
  float* csr_g  = F + off; off += 12288;
  float* asrc   = F + off; off += 189440;
  float* adst   = F + off; off += 189440;
  float* invden = F + off; off += 189440;
  float* y1     = F + off; off += 32768;
  float* WTf    = F + off; off += 61440;
  float* h      = F + off; off += 3031040;
  float* bufB   = F + off; off += 3031040;   // hw16 (bf16, [n][g][c])
  float* bufC   = F + off; off += 3031040;   // g (fp32, [n][g][c])
  float* bufD   = F + off; off += 3031040;   // gh16 (bf16) / z (fp32)
  float* alphaf = F + off; off += (size_t)G_ * E2_ * 4;   // alpha (bf16) / pbuf (fp32)
  float* pbuf   = alphaf;
  int* I        = (int*)(F + off);
  int* counts   = I;
  int* offs     = I + 512;
  int* cursor   = I + 1024;
  int* csr_soff = I + 1536;                  // E2_ entries (12288 slot)
  int2* epack   = (int2*)(I + 13824);        // E2_ int2 entries

  bf* WT     = (bf*)WTf;
  bf* hw16   = (bf*)bufB;
  bf* gh16   = (bf*)bufD;
  bf* alpha16= (bf*)alphaf;

  hipMemsetAsync(deg, 0, 512 * sizeof(float), stream);
  hipMemsetAsync(counts, 0, 512 * sizeof(int), stream);

  k_deg_count<<<48, 256, 0, stream>>>(ei, ew, deg, counts);
  k_gnorm<<<48, 256, 0, stream>>>(ei, ew, deg, gnorm);
  k_scan<<<1, 64, 0, stream>>>(counts, offs, cursor);
  k_fill<<<48, 256, 0, stream>>>(ei, gnorm, cursor, csr_soff, csr_g, epack);
  k_wtr<<<240, 256, 0, stream>>>(W_t, WT);
  hipMemcpyAsync(h, x, (size_t)GN_ * 64 * sizeof(float), hipMemcpyDeviceToDevice, stream);

  for (int l = 0; l < 3; ++l){
    k_rowgemm_t<<<740, 256, 0, stream>>>(h, W_gcn + l * 4096, hw16);
    k_gcn_agg<<<1480, 256, 0, stream>>>(hw16, epack, offs, b_gcn + l * 64, bufC);
    k_rowgemm_attn<<<740, 256, 0, stream>>>(bufC, W_gat + l * 4096, gh16,
                                            att_s + l * 64, att_d + l * 64, asrc, adst);
    k_alpha<<<740, 256, 0, stream>>>(asrc, adst, csr_soff, offs, alpha16, invden);
    k_gat_agg<<<1480, 256, 0, stream>>>(gh16, alpha16, invden, csr_soff, offs,
                                        b_gat + l * 64, ln_g + l * 64, ln_b + l * 64, h);
  }

  k_tfuse<<<BN_, 256, 0, stream>>>(h, WT, b_t, bufD);

  dim3 g1(4, NKC_);
  k_mlp1<<<g1, 256, 0, stream>>>(bufD, W1, pbuf);
  k_red<<<128, 256, 0, stream>>>(pbuf, y1);
  k_mlp2<<<128, 64, 0, stream>>>(y1, b1, W2, b2, outp);
}